// Round 15
// baseline (272.210 us; speedup 1.0000x reference)
//
#include <hip/hip_runtime.h>
#include <math.h>

typedef __attribute__((ext_vector_type(8))) short bf16x8;
typedef __attribute__((ext_vector_type(4))) float f32x4;
typedef __attribute__((ext_vector_type(8))) unsigned short us8;
typedef unsigned short u16;
typedef unsigned int u32;

constexpr int BSZ = 2, SEQ = 2048, DM = 1024, DFF = 4096, NH = 16, DH = 64;
constexpr int MROWS = BSZ * SEQ;  // 4096
constexpr int NREC = BSZ * NH * SEQ;  // 65536 attention rows

__device__ __forceinline__ float bf2f(u16 u) {
  union { unsigned int i; float f; } v; v.i = ((unsigned int)u) << 16; return v.f;
}
__device__ __forceinline__ u16 f2bf(float f) {
  union { float f; unsigned int i; } v; v.f = f;
  unsigned int r = v.i + 0x7fffu + ((v.i >> 16) & 1u);
  return (u16)(r >> 16);
}

#define GLOAD16(gp, lp) __builtin_amdgcn_global_load_lds( \
    (const __attribute__((address_space(1))) void*)(gp),  \
    (__attribute__((address_space(3))) void*)(lp), 16, 0, 0)
#define GLOAD4(gp, lp) __builtin_amdgcn_global_load_lds( \
    (const __attribute__((address_space(1))) void*)(gp),  \
    (__attribute__((address_space(3))) void*)(lp), 4, 0, 0)

// ---------------------------------------------------------------------------
// Fused fp32 -> bf16 convert for ALL weights/activations (one launch).
// ---------------------------------------------------------------------------
__global__ __launch_bounds__(256) void cvt_all(
    const float* __restrict__ x, const float* __restrict__ Wq,
    const float* __restrict__ Wk, const float* __restrict__ Wv,
    const float* __restrict__ Wo, const float* __restrict__ w1,
    const float* __restrict__ w2, u16* __restrict__ xb,
    u16* __restrict__ Wqkvb, u16* __restrict__ Wob,
    u16* __restrict__ w1b, u16* __restrict__ w2b) {
  constexpr int M1 = 1 << 20;
  const int i = (blockIdx.x * 256 + threadIdx.x) * 8;
  const float* src;
  u16* dst;
  int off;
  if (i < 4 * M1)        { src = x;  dst = xb;            off = i;           }
  else if (i < 5 * M1)   { src = Wq; dst = Wqkvb;         off = i - 4 * M1;  }
  else if (i < 6 * M1)   { src = Wk; dst = Wqkvb + M1;    off = i - 5 * M1;  }
  else if (i < 7 * M1)   { src = Wv; dst = Wqkvb + 2 * M1; off = i - 6 * M1; }
  else if (i < 8 * M1)   { src = Wo; dst = Wob;           off = i - 7 * M1;  }
  else if (i < 12 * M1)  { src = w1; dst = w1b;           off = i - 8 * M1;  }
  else                   { src = w2; dst = w2b;           off = i - 12 * M1; }
  const float4 a = *(const float4*)(src + off);
  const float4 b = *(const float4*)(src + off + 4);
  uint4 o;
  o.x = f2bf(a.x) | ((unsigned)f2bf(a.y) << 16);
  o.y = f2bf(a.z) | ((unsigned)f2bf(a.w) << 16);
  o.z = f2bf(b.x) | ((unsigned)f2bf(b.y) << 16);
  o.w = f2bf(b.z) | ((unsigned)f2bf(b.w) << 16);
  *(uint4*)(dst + off) = o;
}

// ---------------------------------------------------------------------------
// bf16 MFMA GEMM, 2-phase double-buffered + XCD swizzle (+ split-K via z).
// ---------------------------------------------------------------------------
template <int BM, int BN, bool BIAS, bool RELU>
__global__ __launch_bounds__(256) void gemm_bf16(
    const u16* __restrict__ A, const u16* __restrict__ B,
    const float* __restrict__ bias, u16* __restrict__ Cb,
    int M, int N, int K, int ld) {
  constexpr int MI = BM / 32, NI = BN / 32;
  __shared__ u16 As[2][BM * 32];
  __shared__ u16 Bs[2][BN * 32];
  const int tid = threadIdx.x;
  const int lane = tid & 63, wid = tid >> 6;

  const int nwg = gridDim.x * gridDim.y;
  int id = blockIdx.y * gridDim.x + blockIdx.x;
  id = (id & 7) * (nwg >> 3) + (id >> 3);
  const int bx = id % gridDim.x, by = id / gridDim.x;

  const u16* Az = A + (size_t)blockIdx.z * K;
  const u16* Bz = B + (size_t)blockIdx.z * K;
  u16* Cz = Cb + (size_t)blockIdx.z * M * N;

  const int row0 = by * BM, col0 = bx * BN;
  const int wr = (wid >> 1) * (BM / 2), wc = (wid & 1) * (BN / 2);
  const int fr = lane & 15, hi = lane >> 4;

  f32x4 acc[MI][NI];
#pragma unroll
  for (int i = 0; i < MI; ++i)
#pragma unroll
    for (int j = 0; j < NI; ++j) acc[i][j] = {0.f, 0.f, 0.f, 0.f};

  const int sr = tid >> 2;
  const int se = (tid & 3) * 8;

#define STAGE(buf, k0)                                                        \
  {                                                                           \
    _Pragma("unroll")                                                         \
    for (int c = 0; c < BM * 64; c += 4096) {                                 \
      const int r = (c >> 6) + sr;                                            \
      GLOAD16(Az + (size_t)(row0 + r) * ld + ((k0) + se),                     \
              ((char*)As[buf]) + c + tid * 16);                               \
    }                                                                         \
    _Pragma("unroll")                                                         \
    for (int c = 0; c < BN * 64; c += 4096) {                                 \
      const int r = (c >> 6) + sr;                                            \
      GLOAD16(Bz + (size_t)(col0 + r) * ld + ((k0) + se),                     \
              ((char*)Bs[buf]) + c + tid * 16);                               \
    }                                                                         \
  }

  STAGE(0, 0);
  __syncthreads();

  const int NIT = K / 32;
  for (int it = 0; it < NIT; ++it) {
    const int cur = it & 1;
    if (it + 1 < NIT) STAGE(cur ^ 1, (it + 1) * 32);

    bf16x8 af[MI], bv[NI];
#pragma unroll
    for (int mi = 0; mi < MI; ++mi)
      af[mi] = *(const bf16x8*)&As[cur][(wr + mi * 16 + fr) * 32 + hi * 8];
#pragma unroll
    for (int ni = 0; ni < NI; ++ni)
      bv[ni] = *(const bf16x8*)&Bs[cur][(wc + ni * 16 + fr) * 32 + hi * 8];
#pragma unroll
    for (int mi = 0; mi < MI; ++mi)
#pragma unroll
      for (int ni = 0; ni < NI; ++ni)
        acc[mi][ni] = __builtin_amdgcn_mfma_f32_16x16x32_bf16(
            af[mi], bv[ni], acc[mi][ni], 0, 0, 0);
    __syncthreads();
  }
#undef STAGE

  const int erow = row0 + wr + (hi << 2);
  const int ecol0 = col0 + wc;
#pragma unroll
  for (int ni = 0; ni < NI; ++ni) {
    const int col = ecol0 + ni * 16 + fr;
    const float bvv = BIAS ? bias[col] : 0.f;
#pragma unroll
    for (int mi = 0; mi < MI; ++mi) {
      const int rbase = erow + mi * 16;
#pragma unroll
      for (int j = 0; j < 4; ++j) {
        float v = acc[mi][ni][j] + bvv;
        if (RELU) v = fmaxf(v, 0.f);
        Cz[(size_t)(rbase + j) * N + col] = f2bf(v);
      }
    }
  }
}

// ---------------------------------------------------------------------------
// MFMA flash attention v7 = v5 + KV-split x2 (blockIdx.z).
// Each split covers 8 of 16 K-tiles; writes unnormalized record per q-row:
// {numerator[64] bf16, m f32 (log2 dom), l f32} = 136 B.
// ---------------------------------------------------------------------------
__global__ __launch_bounds__(512) void attn_mfma(
    const u16* __restrict__ QKV, const int* __restrict__ mask,
    char* __restrict__ Pp) {
  constexpr int KB = 64, QB = 128, NTS = SEQ / KB / 2;  // 8 tiles per split
  __shared__ u16 Kl[2][KB * 64];
  __shared__ u16 Vt[2][64 * KB];
  __shared__ int ml[2][KB];

  const int tid = threadIdx.x;
  const int lane = tid & 63, wid = tid >> 6;
  const int q0 = blockIdx.x * QB;
  const int bh = blockIdx.y;
  const int z = blockIdx.z;
  const int kt0 = z * (SEQ / 2);
  const int b = bh >> 4, h = bh & 15;
  const size_t base = (size_t)b * SEQ * 3072;
  const int fr = lane & 15, g = lane >> 4;

  const u16* qp = QKV + base + (size_t)(q0 + wid * 16 + fr) * 3072 + h * 64 + g * 8;
  bf16x8 qf0, qf1;
  {
    const float QSC = 0.18033688f;  // 0.125 * log2(e)
    const us8 ua = *(const us8*)qp;
    const us8 ub = *(const us8*)(qp + 32);
    u32 pa[4], pb[4];
#pragma unroll
    for (int i = 0; i < 4; ++i) {
      const float a0 = bf2f(ua[2 * i]) * QSC, a1 = bf2f(ua[2 * i + 1]) * QSC;
      const float b0 = bf2f(ub[2 * i]) * QSC, b1 = bf2f(ub[2 * i + 1]) * QSC;
      asm("v_cvt_pk_bf16_f32 %0, %1, %2" : "=v"(pa[i]) : "v"(a0), "v"(a1));
      asm("v_cvt_pk_bf16_f32 %0, %1, %2" : "=v"(pb[i]) : "v"(b0), "v"(b1));
    }
    union { u32 d[4]; bf16x8 v; } c0, c1;
#pragma unroll
    for (int i = 0; i < 4; ++i) { c0.d[i] = pa[i]; c1.d[i] = pb[i]; }
    qf0 = c0.v; qf1 = c1.v;
  }

  const int krow = wid * 8 + (lane >> 3);
  const int kcol = 8 * ((lane & 7) ^ (lane >> 3));
  const u16* ksrc = QKV + base + 1024 + h * 64 + kcol;
  const int kdst = wid * 1024 + lane * 16;

  const int va = (tid & 255) >> 3;
  const int vq = tid & 7;
  const u16* vsrc = QKV + base + 2048 + h * 64 + vq * 8;
  const bool vstage = (wid < 4);

  f32x4 o[4] = {{0.f,0.f,0.f,0.f},{0.f,0.f,0.f,0.f},{0.f,0.f,0.f,0.f},{0.f,0.f,0.f,0.f}};
  float mreg = -3e38f, lreg = 0.f;

  {
    GLOAD16(ksrc + (size_t)(kt0 + krow) * 3072, (char*)Kl[0] + kdst);
    if (wid == 4) GLOAD4(mask + b * SEQ + kt0 + lane, (char*)ml[0] + lane * 4);
    if (vstage) {
      const us8 v0 = *(const us8*)(vsrc + (size_t)(kt0 + 2 * va) * 3072);
      const us8 v1 = *(const us8*)(vsrc + (size_t)(kt0 + 2 * va + 1) * 3072);
      char* vb = (char*)Vt[0];
#pragma unroll
      for (int i = 0; i < 8; ++i) {
        const int d = vq * 8 + i;
        const u32 wv = (u32)(u16)v0[i] | ((u32)(u16)v1[i] << 16);
        *(u32*)(vb + d * 128 + ((4 * va) ^ ((vq ^ i) << 4))) = wv;
      }
    }
  }
  __syncthreads();

  for (int it = 0; it < NTS; ++it) {
    const int cur = it & 1, nxt = cur ^ 1;
    const int ktn = kt0 + (it + 1) * KB;
    const bool pre = (it + 1 < NTS);
    us8 v0 = {}, v1 = {};
    if (pre) {
      GLOAD16(ksrc + (size_t)(ktn + krow) * 3072, (char*)Kl[nxt] + kdst);
      if (wid == 4) GLOAD4(mask + b * SEQ + ktn + lane, (char*)ml[nxt] + lane * 4);
      if (vstage) {
        v0 = *(const us8*)(vsrc + (size_t)(ktn + 2 * va) * 3072);
        v1 = *(const us8*)(vsrc + (size_t)(ktn + 2 * va + 1) * 3072);
      }
    }

    f32x4 s[4];
#pragma unroll
    for (int t16 = 0; t16 < 4; ++t16) {
      const int kr = t16 * 16 + fr;
      const char* krp = (const char*)Kl[cur] + kr * 128;
      const int sw = (kr & 7) << 4;
      const bf16x8 kf0 = *(const bf16x8*)(krp + ((g * 16) ^ sw));
      const bf16x8 kf1 = *(const bf16x8*)(krp + ((g * 16 + 64) ^ sw));
      f32x4 a = {0.f, 0.f, 0.f, 0.f};
      a = __builtin_amdgcn_mfma_f32_16x16x32_bf16(kf0, qf0, a, 0, 0, 0);
      a = __builtin_amdgcn_mfma_f32_16x16x32_bf16(kf1, qf1, a, 0, 0, 0);
      s[t16] = a;
    }

#pragma unroll
    for (int t16 = 0; t16 < 4; ++t16) {
      const int4 mv = *(const int4*)&ml[cur][t16 * 16 + g * 4];
      const int* mp = (const int*)&mv;
#pragma unroll
      for (int j = 0; j < 4; ++j)
        if (mp[j] == 0) s[t16][j] = -3e38f;
    }

    float rmax = s[0][0];
#pragma unroll
    for (int t16 = 0; t16 < 4; ++t16)
#pragma unroll
      for (int j = 0; j < 4; ++j) rmax = fmaxf(rmax, s[t16][j]);

    if (!__all(rmax <= mreg + 12.f)) {
      rmax = fmaxf(rmax, __shfl_xor(rmax, 16));
      rmax = fmaxf(rmax, __shfl_xor(rmax, 32));
      const float mn = fmaxf(mreg, rmax);
      float sc;
      asm("v_exp_f32 %0, %1" : "=v"(sc) : "v"(mreg - mn));
      mreg = mn;
      lreg *= sc;
#pragma unroll
      for (int j = 0; j < 4; ++j) {
        const float scj = __shfl(sc, (g << 4) + g * 4 + j);
#pragma unroll
        for (int dt = 0; dt < 4; ++dt) o[dt][j] *= scj;
      }
    }

    float p[4][4];
#pragma unroll
    for (int t16 = 0; t16 < 4; ++t16)
#pragma unroll
      for (int j = 0; j < 4; ++j) {
        float e;
        asm("v_exp_f32 %0, %1" : "=v"(e) : "v"(s[t16][j] - mreg));
        p[t16][j] = e;
        lreg += e;
      }

    u32 plo[4], phi[4];
#pragma unroll
    for (int t16 = 0; t16 < 4; ++t16) {
      asm("v_cvt_pk_bf16_f32 %0, %1, %2"
          : "=v"(plo[t16]) : "v"(p[t16][0]), "v"(p[t16][1]));
      asm("v_cvt_pk_bf16_f32 %0, %1, %2"
          : "=v"(phi[t16]) : "v"(p[t16][2]), "v"(p[t16][3]));
    }

#pragma unroll
    for (int kh = 0; kh < 2; ++kh) {
      u32 fd[4];
#pragma unroll
      for (int hf = 0; hf < 2; ++hf) {
        const int sl = fr + ((((g & 1) << 1) + hf) << 4);
        const u32 c0l = (u32)__shfl((int)plo[kh * 2], sl);
        const u32 c0h = (u32)__shfl((int)phi[kh * 2], sl);
        const u32 c1l = (u32)__shfl((int)plo[kh * 2 + 1], sl);
        const u32 c1h = (u32)__shfl((int)phi[kh * 2 + 1], sl);
        const bool s1 = ((g >> 1) & 1) != 0;
        fd[hf * 2] = s1 ? c1l : c0l;
        fd[hf * 2 + 1] = s1 ? c1h : c0h;
      }
      union { u32 d[4]; bf16x8 v; } uu;
      uu.d[0] = fd[0]; uu.d[1] = fd[1]; uu.d[2] = fd[2]; uu.d[3] = fd[3];
      const bf16x8 pf = uu.v;
#pragma unroll
      for (int dt = 0; dt < 4; ++dt) {
        const int d = dt * 16 + fr;
        const int xd = (((d >> 3) ^ d) & 7) << 4;
        const bf16x8 vf = *(const bf16x8*)((const char*)Vt[cur] + d * 128 +
                                           ((g * 16 + kh * 64) ^ xd));
        o[dt] = __builtin_amdgcn_mfma_f32_16x16x32_bf16(pf, vf, o[dt], 0, 0, 0);
      }
    }

    if (pre && vstage) {
      char* vb = (char*)Vt[nxt];
#pragma unroll
      for (int i = 0; i < 8; ++i) {
        const int d = vq * 8 + i;
        const u32 wv = (u32)(u16)v0[i] | ((u32)(u16)v1[i] << 16);
        *(u32*)(vb + d * 128 + ((4 * va) ^ ((vq ^ i) << 4))) = wv;
      }
    }
    __syncthreads();
  }

  // ---- epilogue: write unnormalized record {num[64] bf16, m, l}
  lreg += __shfl_xor(lreg, 16);
  lreg += __shfl_xor(lreg, 32);
#pragma unroll
  for (int j = 0; j < 4; ++j) {
    const int sl = (g << 4) + g * 4 + j;
    const float lj = __shfl(lreg, sl);
    const float mj = __shfl(mreg, sl);
    const int qrow = q0 + wid * 16 + g * 4 + j;
    const int r = bh * SEQ + qrow;
    char* rec = Pp + ((size_t)z * NREC + r) * 136;
    u16* rn = (u16*)rec;
#pragma unroll
    for (int dt = 0; dt < 4; ++dt)
      rn[dt * 16 + fr] = f2bf(o[dt][j]);
    if (fr == 0) {
      ((float*)rec)[32] = mj;
      ((float*)rec)[33] = lj;
    }
  }
}

// ---------------------------------------------------------------------------
// Combine 2 KV-split partials -> bf16 O. 1 wave per q-row (lane = d).
// ---------------------------------------------------------------------------
__global__ __launch_bounds__(256) void attn_combine(
    const char* __restrict__ Pp, u16* __restrict__ Ob) {
  const int tid = threadIdx.x;
  const int w = tid >> 6, d = tid & 63;
  const int r = blockIdx.x * 4 + w;  // bh*SEQ + q
  const char* r0 = Pp + (size_t)r * 136;
  const char* r1 = r0 + (size_t)NREC * 136;
  const float m0 = *(const float*)(r0 + 128), l0 = *(const float*)(r0 + 132);
  const float m1 = *(const float*)(r1 + 128), l1 = *(const float*)(r1 + 132);
  const float M = fmaxf(m0, m1);
  float w0, w1;
  asm("v_exp_f32 %0, %1" : "=v"(w0) : "v"(m0 - M));  // exp2 (log2 domain)
  asm("v_exp_f32 %0, %1" : "=v"(w1) : "v"(m1 - M));
  const float n0 = bf2f(((const u16*)r0)[d]);
  const float n1 = bf2f(((const u16*)r1)[d]);
  const float num = w0 * n0 + w1 * n1;
  const float den = w0 * l0 + w1 * l1;
  const int bh = r >> 11, q = r & 2047;
  const int b = bh >> 4, h = bh & 15;
  Ob[((size_t)(b * SEQ + q)) * DM + h * 64 + d] = f2bf(num / den);
}

// ---------------------------------------------------------------------------
// Fused residual-add + LayerNorm with up to 3 bf16 addends + optional bias.
// ---------------------------------------------------------------------------
template <bool OBF, bool HASC, bool HASB>
__global__ __launch_bounds__(256) void ln_add(
    const u16* __restrict__ Ap, const u16* __restrict__ Bp,
    const u16* __restrict__ Cp, const float* __restrict__ bias,
    const float* __restrict__ g, const float* __restrict__ be,
    void* __restrict__ outp) {
  __shared__ float red[2][4];
  __shared__ float mu_s, sig_s;
  const int row = blockIdx.x;
  const int tid = threadIdx.x;
  const size_t off = (size_t)row * DM + tid * 4;

  const ushort4 ua = *(const ushort4*)(Ap + off);
  const ushort4 ub = *(const ushort4*)(Bp + off);
  float4 s = make_float4(bf2f(ua.x) + bf2f(ub.x), bf2f(ua.y) + bf2f(ub.y),
                         bf2f(ua.z) + bf2f(ub.z), bf2f(ua.w) + bf2f(ub.w));
  if (HASC) {
    const ushort4 uc = *(const ushort4*)(Cp + off);
    s.x += bf2f(uc.x); s.y += bf2f(uc.y); s.z += bf2f(uc.z); s.w += bf2f(uc.w);
  }
  if (HASB) {
    const float4 bb = *(const float4*)(bias + tid * 4);
    s.x += bb.x; s.y += bb.y; s.z += bb.z; s.w += bb.w;
  }

  float sum = s.x + s.y + s.z + s.w;
  float sq = s.x * s.x + s.y * s.y + s.z * s.z + s.w * s.w;
#pragma unroll
  for (int off2 = 32; off2 >= 1; off2 >>= 1) {
    sum += __shfl_xor(sum, off2);
    sq += __shfl_xor(sq, off2);
  }
  const int wid = tid >> 6;
  if ((tid & 63) == 0) { red[0][wid] = sum; red[1][wid] = sq; }
  __syncthreads();
  if (tid == 0) {
    float ts = red[0][0] + red[0][1] + red[0][2] + red[0][3];
    float tq = red[1][0] + red[1][1] + red[1][2] + red[1][3];
    float mu = ts * (1.f / DM);
    float var = tq * (1.f / DM) - mu * mu;
    mu_s = mu;
    sig_s = sqrtf(fmaxf(var, 0.f)) + 1e-6f;
  }
  __syncthreads();
  const float mu = mu_s, inv = 1.f / sig_s;
  const float4 gv = *(const float4*)(g + tid * 4);
  const float4 bv = *(const float4*)(be + tid * 4);
  float4 o;
  o.x = (s.x - mu) * inv * gv.x + bv.x;
  o.y = (s.y - mu) * inv * gv.y + bv.y;
  o.z = (s.z - mu) * inv * gv.z + bv.z;
  o.w = (s.w - mu) * inv * gv.w + bv.w;
  if (OBF) {
    u16* op = (u16*)outp + off;
    ushort4 o4;
    o4.x = f2bf(o.x); o4.y = f2bf(o.y); o4.z = f2bf(o.z); o4.w = f2bf(o.w);
    *(ushort4*)op = o4;
  } else {
    *(float4*)((float*)outp + off) = o;
  }
}

// ---------------------------------------------------------------------------
extern "C" void kernel_launch(void* const* d_in, const int* in_sizes, int n_in,
                              void* d_out, int out_size, void* d_ws,
                              size_t ws_size, hipStream_t stream) {
  const float* x  = (const float*)d_in[0];
  const int* mask = (const int*)d_in[1];
  const float* Wq = (const float*)d_in[2];
  const float* Wk = (const float*)d_in[3];
  const float* Wv = (const float*)d_in[4];
  const float* Wo = (const float*)d_in[5];
  const float* w1 = (const float*)d_in[6];
  const float* b1 = (const float*)d_in[7];
  const float* w2 = (const float*)d_in[8];
  const float* b2 = (const float*)d_in[9];
  const float* g1 = (const float*)d_in[10];
  const float* be1 = (const float*)d_in[11];
  const float* g2 = (const float*)d_in[12];
  const float* be2 = (const float*)d_in[13];
  float* out = (float*)d_out;
  float* ws = (float*)d_ws;

  // workspace layout (float offsets) — live-range-checked:
  //  QKVb  [0        .. 6291456)   4096x3072 bf16
  //  xb    [6291456  .. 8388608)   4096x1024 bf16
  //  Wqkvb [8388608  .. 9961472)   3072x1024 bf16
  //  Wob   [9961472  .. 10485760)  1024x1024 bf16
  //  w1b   [10485760 .. 12582912)  4096x1024 bf16
  //  w2b   [12582912 .. 14680064)  1024x4096 bf16
  //  Obf   [14680064 .. 16777216)  4096x1024 bf16
  //  Pp    [16777216 .. 21233664)  2x65536x34 f32 (attn partials; dead
  //                                 after combine, before X1a/X2b writes)
  //  X1a   [16777216 .. 18874368)  4096x1024 bf16 (split-K partial 0)
  //  X1c   [18874368 .. 20971520)  4096x1024 bf16 (split-K partial 1)
  //  X2b   [20971520 .. 23068672)  4096x1024 bf16 (written after Pp dead)
  //  X3a   [23068672 .. 25165824)  4096x1024 bf16
  //  X3c   [25165824 .. 27262976)  4096x1024 bf16
  //  Hb    [0        .. 8388608)   4096x4096 bf16 (reuses QKVb+xb)
  u16*   QKVb  = (u16*)(ws + 0);
  u16*   xb    = (u16*)(ws + 6291456);
  u16*   Wqkvb = (u16*)(ws + 8388608);
  u16*   Wob   = (u16*)(ws + 9961472);
  u16*   w1b   = (u16*)(ws + 10485760);
  u16*   w2b   = (u16*)(ws + 12582912);
  u16*   Obf   = (u16*)(ws + 14680064);
  char*  Pp    = (char*)(ws + 16777216);
  u16*   X1a   = (u16*)(ws + 16777216);
  u16*   X1c   = (u16*)(ws + 18874368);
  u16*   X2b   = (u16*)(ws + 20971520);
  u16*   X3a   = (u16*)(ws + 23068672);
  u16*   X3c   = (u16*)(ws + 25165824);
  u16*   Hb    = (u16*)(ws + 0);

  const dim3 blk(256);

  cvt_all<<<8192, blk, 0, stream>>>(x, Wq, Wk, Wv, Wo, w1, w2,
                                    xb, Wqkvb, Wob, w1b, w2b);

  // fused QKV projection: [4096,3072] = xb @ Wqkvb^T, bf16 out
  gemm_bf16<128, 128, false, false><<<dim3(3072 / 128, MROWS / 128), blk, 0, stream>>>(
      xb, Wqkvb, nullptr, QKVb, MROWS, 3072, DM, DM);

  // MFMA flash attention v7, KV-split x2 -> partials Pp
  attn_mfma<<<dim3(SEQ / 128, BSZ * NH, 2), dim3(512), 0, stream>>>(QKVb, mask, Pp);
  attn_combine<<<dim3(NREC / 4), blk, 0, stream>>>(Pp, Obf);

  // X1 = O @ Wo^T, split-K x2 (partials X1a, X1c; summed in LN1)
  gemm_bf16<64, 128, false, false><<<dim3(DM / 128, MROWS / 64, 2), blk, 0, stream>>>(
      Obf, Wob, nullptr, X1a, MROWS, DM, DM / 2, DM);

  // X2 = LN(X1a + X1c + xb) -> bf16
  ln_add<true, true, false><<<dim3(MROWS), blk, 0, stream>>>(
      X1a, xb, X1c, nullptr, g1, be1, X2b);

  // H = relu(X2 @ w1^T + b1) -> bf16
  gemm_bf16<128, 128, true, true><<<dim3(DFF / 128, MROWS / 128), blk, 0, stream>>>(
      X2b, w1b, b1, Hb, MROWS, DFF, DM, DM);

  // X3 = H @ w2^T, split-K x2 (partials X3a, X3c; bias b2 added in LN2)
  gemm_bf16<64, 128, false, false><<<dim3(DM / 128, MROWS / 64, 2), blk, 0, stream>>>(
      Hb, w2b, nullptr, X3a, MROWS, DM, DFF / 2, DFF);

  // out = LN(X2 + X3a + X3c + b2) -> fp32
  ln_add<false, true, true><<<dim3(MROWS), blk, 0, stream>>>(
      X2b, X3a, X3c, b2, g2, be2, out);
}

// Round 16
// 262.110 us; speedup vs baseline: 1.0385x; 1.0385x over previous
//
#include <hip/hip_runtime.h>
#include <math.h>

typedef __attribute__((ext_vector_type(8))) short bf16x8;
typedef __attribute__((ext_vector_type(4))) float f32x4;
typedef __attribute__((ext_vector_type(8))) unsigned short us8;
typedef unsigned short u16;
typedef unsigned int u32;

constexpr int BSZ = 2, SEQ = 2048, DM = 1024, DFF = 4096, NH = 16, DH = 64;
constexpr int MROWS = BSZ * SEQ;  // 4096

__device__ __forceinline__ float bf2f(u16 u) {
  union { unsigned int i; float f; } v; v.i = ((unsigned int)u) << 16; return v.f;
}
__device__ __forceinline__ u16 f2bf(float f) {
  union { float f; unsigned int i; } v; v.f = f;
  unsigned int r = v.i + 0x7fffu + ((v.i >> 16) & 1u);
  return (u16)(r >> 16);
}

#define GLOAD16(gp, lp) __builtin_amdgcn_global_load_lds( \
    (const __attribute__((address_space(1))) void*)(gp),  \
    (__attribute__((address_space(3))) void*)(lp), 16, 0, 0)
#define GLOAD4(gp, lp) __builtin_amdgcn_global_load_lds( \
    (const __attribute__((address_space(1))) void*)(gp),  \
    (__attribute__((address_space(3))) void*)(lp), 4, 0, 0)

// ---------------------------------------------------------------------------
// Fused fp32 -> bf16 convert for ALL weights/activations (one launch).
// ---------------------------------------------------------------------------
__global__ __launch_bounds__(256) void cvt_all(
    const float* __restrict__ x, const float* __restrict__ Wq,
    const float* __restrict__ Wk, const float* __restrict__ Wv,
    const float* __restrict__ Wo, const float* __restrict__ w1,
    const float* __restrict__ w2, u16* __restrict__ xb,
    u16* __restrict__ Wqkvb, u16* __restrict__ Wob,
    u16* __restrict__ w1b, u16* __restrict__ w2b) {
  constexpr int M1 = 1 << 20;
  const int i = (blockIdx.x * 256 + threadIdx.x) * 8;
  const float* src;
  u16* dst;
  int off;
  if (i < 4 * M1)        { src = x;  dst = xb;            off = i;           }
  else if (i < 5 * M1)   { src = Wq; dst = Wqkvb;         off = i - 4 * M1;  }
  else if (i < 6 * M1)   { src = Wk; dst = Wqkvb + M1;    off = i - 5 * M1;  }
  else if (i < 7 * M1)   { src = Wv; dst = Wqkvb + 2 * M1; off = i - 6 * M1; }
  else if (i < 8 * M1)   { src = Wo; dst = Wob;           off = i - 7 * M1;  }
  else if (i < 12 * M1)  { src = w1; dst = w1b;           off = i - 8 * M1;  }
  else                   { src = w2; dst = w2b;           off = i - 12 * M1; }
  const float4 a = *(const float4*)(src + off);
  const float4 b = *(const float4*)(src + off + 4);
  uint4 o;
  o.x = f2bf(a.x) | ((unsigned)f2bf(a.y) << 16);
  o.y = f2bf(a.z) | ((unsigned)f2bf(a.w) << 16);
  o.z = f2bf(b.x) | ((unsigned)f2bf(b.y) << 16);
  o.w = f2bf(b.z) | ((unsigned)f2bf(b.w) << 16);
  *(uint4*)(dst + off) = o;
}

// ---------------------------------------------------------------------------
// bf16 MFMA GEMM, 2-phase double-buffered + XCD swizzle (+ split-K via z).
// C[M,N] = A[M,0..K) * B[N,0..K)^T with row stride ld. Block z covers
// k in [z*K,(z+1)*K), partial to Cb + z*M*N. BK=32, 256 thr = 4 waves.
// ---------------------------------------------------------------------------
template <int BM, int BN, bool BIAS, bool RELU>
__global__ __launch_bounds__(256) void gemm_bf16(
    const u16* __restrict__ A, const u16* __restrict__ B,
    const float* __restrict__ bias, u16* __restrict__ Cb,
    int M, int N, int K, int ld) {
  constexpr int MI = BM / 32, NI = BN / 32;
  __shared__ u16 As[2][BM * 32];
  __shared__ u16 Bs[2][BN * 32];
  const int tid = threadIdx.x;
  const int lane = tid & 63, wid = tid >> 6;

  const int nwg = gridDim.x * gridDim.y;
  int id = blockIdx.y * gridDim.x + blockIdx.x;
  id = (id & 7) * (nwg >> 3) + (id >> 3);
  const int bx = id % gridDim.x, by = id / gridDim.x;

  const u16* Az = A + (size_t)blockIdx.z * K;
  const u16* Bz = B + (size_t)blockIdx.z * K;
  u16* Cz = Cb + (size_t)blockIdx.z * M * N;

  const int row0 = by * BM, col0 = bx * BN;
  const int wr = (wid >> 1) * (BM / 2), wc = (wid & 1) * (BN / 2);
  const int fr = lane & 15, hi = lane >> 4;

  f32x4 acc[MI][NI];
#pragma unroll
  for (int i = 0; i < MI; ++i)
#pragma unroll
    for (int j = 0; j < NI; ++j) acc[i][j] = {0.f, 0.f, 0.f, 0.f};

  const int sr = tid >> 2;
  const int se = (tid & 3) * 8;

#define STAGE(buf, k0)                                                        \
  {                                                                           \
    _Pragma("unroll")                                                         \
    for (int c = 0; c < BM * 64; c += 4096) {                                 \
      const int r = (c >> 6) + sr;                                            \
      GLOAD16(Az + (size_t)(row0 + r) * ld + ((k0) + se),                     \
              ((char*)As[buf]) + c + tid * 16);                               \
    }                                                                         \
    _Pragma("unroll")                                                         \
    for (int c = 0; c < BN * 64; c += 4096) {                                 \
      const int r = (c >> 6) + sr;                                            \
      GLOAD16(Bz + (size_t)(col0 + r) * ld + ((k0) + se),                     \
              ((char*)Bs[buf]) + c + tid * 16);                               \
    }                                                                         \
  }

  STAGE(0, 0);
  __syncthreads();

  const int NIT = K / 32;
  for (int it = 0; it < NIT; ++it) {
    const int cur = it & 1;
    if (it + 1 < NIT) STAGE(cur ^ 1, (it + 1) * 32);

    bf16x8 af[MI], bv[NI];
#pragma unroll
    for (int mi = 0; mi < MI; ++mi)
      af[mi] = *(const bf16x8*)&As[cur][(wr + mi * 16 + fr) * 32 + hi * 8];
#pragma unroll
    for (int ni = 0; ni < NI; ++ni)
      bv[ni] = *(const bf16x8*)&Bs[cur][(wc + ni * 16 + fr) * 32 + hi * 8];
#pragma unroll
    for (int mi = 0; mi < MI; ++mi)
#pragma unroll
      for (int ni = 0; ni < NI; ++ni)
        acc[mi][ni] = __builtin_amdgcn_mfma_f32_16x16x32_bf16(
            af[mi], bv[ni], acc[mi][ni], 0, 0, 0);
    __syncthreads();
  }
#undef STAGE

  const int erow = row0 + wr + (hi << 2);
  const int ecol0 = col0 + wc;
#pragma unroll
  for (int ni = 0; ni < NI; ++ni) {
    const int col = ecol0 + ni * 16 + fr;
    const float bvv = BIAS ? bias[col] : 0.f;
#pragma unroll
    for (int mi = 0; mi < MI; ++mi) {
      const int rbase = erow + mi * 16;
#pragma unroll
      for (int j = 0; j < 4; ++j) {
        float v = acc[mi][ni][j] + bvv;
        if (RELU) v = fmaxf(v, 0.f);
        Cz[(size_t)(rbase + j) * N + col] = f2bf(v);
      }
    }
  }
}

// ---------------------------------------------------------------------------
// MFMA flash attention v5 (round-10/14 winner, restored).
// 512 thr = 8 waves, QB=128, KB=64. Log2-domain scores, defer-max,
// per-lane partial l, cvt_pk P-pack, register-P shfl gather.
// NOTE (r15): KV-split x2 gave 0 gain at unchanged occupancy -> kernel is
// per-CU pipe-throughput-bound, not latency-bound. Do not re-split.
// ---------------------------------------------------------------------------
__global__ __launch_bounds__(512) void attn_mfma(
    const u16* __restrict__ QKV, const int* __restrict__ mask,
    u16* __restrict__ Ob) {
  constexpr int KB = 64, QB = 128, NT = SEQ / KB;
  __shared__ u16 Kl[2][KB * 64];
  __shared__ u16 Vt[2][64 * KB];
  __shared__ int ml[2][KB];

  const int tid = threadIdx.x;
  const int lane = tid & 63, wid = tid >> 6;
  const int q0 = blockIdx.x * QB;
  const int bh = blockIdx.y;
  const int b = bh >> 4, h = bh & 15;
  const size_t base = (size_t)b * SEQ * 3072;
  const int fr = lane & 15, g = lane >> 4;

  const u16* qp = QKV + base + (size_t)(q0 + wid * 16 + fr) * 3072 + h * 64 + g * 8;
  bf16x8 qf0, qf1;
  {
    const float QSC = 0.18033688f;  // 0.125 * log2(e)
    const us8 ua = *(const us8*)qp;
    const us8 ub = *(const us8*)(qp + 32);
    u32 pa[4], pb[4];
#pragma unroll
    for (int i = 0; i < 4; ++i) {
      const float a0 = bf2f(ua[2 * i]) * QSC, a1 = bf2f(ua[2 * i + 1]) * QSC;
      const float b0 = bf2f(ub[2 * i]) * QSC, b1 = bf2f(ub[2 * i + 1]) * QSC;
      asm("v_cvt_pk_bf16_f32 %0, %1, %2" : "=v"(pa[i]) : "v"(a0), "v"(a1));
      asm("v_cvt_pk_bf16_f32 %0, %1, %2" : "=v"(pb[i]) : "v"(b0), "v"(b1));
    }
    union { u32 d[4]; bf16x8 v; } c0, c1;
#pragma unroll
    for (int i = 0; i < 4; ++i) { c0.d[i] = pa[i]; c1.d[i] = pb[i]; }
    qf0 = c0.v; qf1 = c1.v;
  }

  const int krow = wid * 8 + (lane >> 3);
  const int kcol = 8 * ((lane & 7) ^ (lane >> 3));
  const u16* ksrc = QKV + base + 1024 + h * 64 + kcol;
  const int kdst = wid * 1024 + lane * 16;

  const int va = (tid & 255) >> 3;
  const int vq = tid & 7;
  const u16* vsrc = QKV + base + 2048 + h * 64 + vq * 8;
  const bool vstage = (wid < 4);

  f32x4 o[4] = {{0.f,0.f,0.f,0.f},{0.f,0.f,0.f,0.f},{0.f,0.f,0.f,0.f},{0.f,0.f,0.f,0.f}};
  float mreg = -3e38f, lreg = 0.f;

  {
    GLOAD16(ksrc + (size_t)krow * 3072, (char*)Kl[0] + kdst);
    if (wid == 4) GLOAD4(mask + b * SEQ + lane, (char*)ml[0] + lane * 4);
    if (vstage) {
      const us8 v0 = *(const us8*)(vsrc + (size_t)(2 * va) * 3072);
      const us8 v1 = *(const us8*)(vsrc + (size_t)(2 * va + 1) * 3072);
      char* vb = (char*)Vt[0];
#pragma unroll
      for (int i = 0; i < 8; ++i) {
        const int d = vq * 8 + i;
        const u32 wv = (u32)(u16)v0[i] | ((u32)(u16)v1[i] << 16);
        *(u32*)(vb + d * 128 + ((4 * va) ^ ((vq ^ i) << 4))) = wv;
      }
    }
  }
  __syncthreads();

  for (int it = 0; it < NT; ++it) {
    const int cur = it & 1, nxt = cur ^ 1;
    const int ktn = (it + 1) * KB;
    const bool pre = (it + 1 < NT);
    us8 v0 = {}, v1 = {};
    if (pre) {
      GLOAD16(ksrc + (size_t)(ktn + krow) * 3072, (char*)Kl[nxt] + kdst);
      if (wid == 4) GLOAD4(mask + b * SEQ + ktn + lane, (char*)ml[nxt] + lane * 4);
      if (vstage) {
        v0 = *(const us8*)(vsrc + (size_t)(ktn + 2 * va) * 3072);
        v1 = *(const us8*)(vsrc + (size_t)(ktn + 2 * va + 1) * 3072);
      }
    }

    f32x4 s[4];
#pragma unroll
    for (int t16 = 0; t16 < 4; ++t16) {
      const int kr = t16 * 16 + fr;
      const char* krp = (const char*)Kl[cur] + kr * 128;
      const int sw = (kr & 7) << 4;
      const bf16x8 kf0 = *(const bf16x8*)(krp + ((g * 16) ^ sw));
      const bf16x8 kf1 = *(const bf16x8*)(krp + ((g * 16 + 64) ^ sw));
      f32x4 a = {0.f, 0.f, 0.f, 0.f};
      a = __builtin_amdgcn_mfma_f32_16x16x32_bf16(kf0, qf0, a, 0, 0, 0);
      a = __builtin_amdgcn_mfma_f32_16x16x32_bf16(kf1, qf1, a, 0, 0, 0);
      s[t16] = a;
    }

#pragma unroll
    for (int t16 = 0; t16 < 4; ++t16) {
      const int4 mv = *(const int4*)&ml[cur][t16 * 16 + g * 4];
      const int* mp = (const int*)&mv;
#pragma unroll
      for (int j = 0; j < 4; ++j)
        if (mp[j] == 0) s[t16][j] = -3e38f;
    }

    float rmax = s[0][0];
#pragma unroll
    for (int t16 = 0; t16 < 4; ++t16)
#pragma unroll
      for (int j = 0; j < 4; ++j) rmax = fmaxf(rmax, s[t16][j]);

    if (!__all(rmax <= mreg + 12.f)) {
      rmax = fmaxf(rmax, __shfl_xor(rmax, 16));
      rmax = fmaxf(rmax, __shfl_xor(rmax, 32));
      const float mn = fmaxf(mreg, rmax);
      float sc;
      asm("v_exp_f32 %0, %1" : "=v"(sc) : "v"(mreg - mn));
      mreg = mn;
      lreg *= sc;
#pragma unroll
      for (int j = 0; j < 4; ++j) {
        const float scj = __shfl(sc, (g << 4) + g * 4 + j);
#pragma unroll
        for (int dt = 0; dt < 4; ++dt) o[dt][j] *= scj;
      }
    }

    float p[4][4];
#pragma unroll
    for (int t16 = 0; t16 < 4; ++t16)
#pragma unroll
      for (int j = 0; j < 4; ++j) {
        float e;
        asm("v_exp_f32 %0, %1" : "=v"(e) : "v"(s[t16][j] - mreg));
        p[t16][j] = e;
        lreg += e;
      }

    u32 plo[4], phi[4];
#pragma unroll
    for (int t16 = 0; t16 < 4; ++t16) {
      asm("v_cvt_pk_bf16_f32 %0, %1, %2"
          : "=v"(plo[t16]) : "v"(p[t16][0]), "v"(p[t16][1]));
      asm("v_cvt_pk_bf16_f32 %0, %1, %2"
          : "=v"(phi[t16]) : "v"(p[t16][2]), "v"(p[t16][3]));
    }

#pragma unroll
    for (int kh = 0; kh < 2; ++kh) {
      u32 fd[4];
#pragma unroll
      for (int hf = 0; hf < 2; ++hf) {
        const int sl = fr + ((((g & 1) << 1) + hf) << 4);
        const u32 c0l = (u32)__shfl((int)plo[kh * 2], sl);
        const u32 c0h = (u32)__shfl((int)phi[kh * 2], sl);
        const u32 c1l = (u32)__shfl((int)plo[kh * 2 + 1], sl);
        const u32 c1h = (u32)__shfl((int)phi[kh * 2 + 1], sl);
        const bool s1 = ((g >> 1) & 1) != 0;
        fd[hf * 2] = s1 ? c1l : c0l;
        fd[hf * 2 + 1] = s1 ? c1h : c0h;
      }
      union { u32 d[4]; bf16x8 v; } uu;
      uu.d[0] = fd[0]; uu.d[1] = fd[1]; uu.d[2] = fd[2]; uu.d[3] = fd[3];
      const bf16x8 pf = uu.v;
#pragma unroll
      for (int dt = 0; dt < 4; ++dt) {
        const int d = dt * 16 + fr;
        const int xd = (((d >> 3) ^ d) & 7) << 4;
        const bf16x8 vf = *(const bf16x8*)((const char*)Vt[cur] + d * 128 +
                                           ((g * 16 + kh * 64) ^ xd));
        o[dt] = __builtin_amdgcn_mfma_f32_16x16x32_bf16(pf, vf, o[dt], 0, 0, 0);
      }
    }

    if (pre && vstage) {
      char* vb = (char*)Vt[nxt];
#pragma unroll
      for (int i = 0; i < 8; ++i) {
        const int d = vq * 8 + i;
        const u32 wv = (u32)(u16)v0[i] | ((u32)(u16)v1[i] << 16);
        *(u32*)(vb + d * 128 + ((4 * va) ^ ((vq ^ i) << 4))) = wv;
      }
    }
    __syncthreads();
  }

  lreg += __shfl_xor(lreg, 16);
  lreg += __shfl_xor(lreg, 32);
  const float inv = 1.f / lreg;
#pragma unroll
  for (int j = 0; j < 4; ++j) {
    const float invj = __shfl(inv, (g << 4) + g * 4 + j);
    const int qrow = q0 + wid * 16 + g * 4 + j;
    u16* orow = Ob + (size_t)(b * SEQ + qrow) * DM + h * 64;
#pragma unroll
    for (int dt = 0; dt < 4; ++dt)
      orow[dt * 16 + fr] = f2bf(o[dt][j] * invj);
  }
}

// ---------------------------------------------------------------------------
// Fused residual-add + LayerNorm with up to 3 bf16 addends + optional bias.
// ---------------------------------------------------------------------------
template <bool OBF, bool HASC, bool HASB>
__global__ __launch_bounds__(256) void ln_add(
    const u16* __restrict__ Ap, const u16* __restrict__ Bp,
    const u16* __restrict__ Cp, const float* __restrict__ bias,
    const float* __restrict__ g, const float* __restrict__ be,
    void* __restrict__ outp) {
  __shared__ float red[2][4];
  __shared__ float mu_s, sig_s;
  const int row = blockIdx.x;
  const int tid = threadIdx.x;
  const size_t off = (size_t)row * DM + tid * 4;

  const ushort4 ua = *(const ushort4*)(Ap + off);
  const ushort4 ub = *(const ushort4*)(Bp + off);
  float4 s = make_float4(bf2f(ua.x) + bf2f(ub.x), bf2f(ua.y) + bf2f(ub.y),
                         bf2f(ua.z) + bf2f(ub.z), bf2f(ua.w) + bf2f(ub.w));
  if (HASC) {
    const ushort4 uc = *(const ushort4*)(Cp + off);
    s.x += bf2f(uc.x); s.y += bf2f(uc.y); s.z += bf2f(uc.z); s.w += bf2f(uc.w);
  }
  if (HASB) {
    const float4 bb = *(const float4*)(bias + tid * 4);
    s.x += bb.x; s.y += bb.y; s.z += bb.z; s.w += bb.w;
  }

  float sum = s.x + s.y + s.z + s.w;
  float sq = s.x * s.x + s.y * s.y + s.z * s.z + s.w * s.w;
#pragma unroll
  for (int off2 = 32; off2 >= 1; off2 >>= 1) {
    sum += __shfl_xor(sum, off2);
    sq += __shfl_xor(sq, off2);
  }
  const int wid = tid >> 6;
  if ((tid & 63) == 0) { red[0][wid] = sum; red[1][wid] = sq; }
  __syncthreads();
  if (tid == 0) {
    float ts = red[0][0] + red[0][1] + red[0][2] + red[0][3];
    float tq = red[1][0] + red[1][1] + red[1][2] + red[1][3];
    float mu = ts * (1.f / DM);
    float var = tq * (1.f / DM) - mu * mu;
    mu_s = mu;
    sig_s = sqrtf(fmaxf(var, 0.f)) + 1e-6f;
  }
  __syncthreads();
  const float mu = mu_s, inv = 1.f / sig_s;
  const float4 gv = *(const float4*)(g + tid * 4);
  const float4 bv = *(const float4*)(be + tid * 4);
  float4 o;
  o.x = (s.x - mu) * inv * gv.x + bv.x;
  o.y = (s.y - mu) * inv * gv.y + bv.y;
  o.z = (s.z - mu) * inv * gv.z + bv.z;
  o.w = (s.w - mu) * inv * gv.w + bv.w;
  if (OBF) {
    u16* op = (u16*)outp + off;
    ushort4 o4;
    o4.x = f2bf(o.x); o4.y = f2bf(o.y); o4.z = f2bf(o.z); o4.w = f2bf(o.w);
    *(ushort4*)op = o4;
  } else {
    *(float4*)((float*)outp + off) = o;
  }
}

// ---------------------------------------------------------------------------
extern "C" void kernel_launch(void* const* d_in, const int* in_sizes, int n_in,
                              void* d_out, int out_size, void* d_ws,
                              size_t ws_size, hipStream_t stream) {
  const float* x  = (const float*)d_in[0];
  const int* mask = (const int*)d_in[1];
  const float* Wq = (const float*)d_in[2];
  const float* Wk = (const float*)d_in[3];
  const float* Wv = (const float*)d_in[4];
  const float* Wo = (const float*)d_in[5];
  const float* w1 = (const float*)d_in[6];
  const float* b1 = (const float*)d_in[7];
  const float* w2 = (const float*)d_in[8];
  const float* b2 = (const float*)d_in[9];
  const float* g1 = (const float*)d_in[10];
  const float* be1 = (const float*)d_in[11];
  const float* g2 = (const float*)d_in[12];
  const float* be2 = (const float*)d_in[13];
  float* out = (float*)d_out;
  float* ws = (float*)d_ws;

  // workspace layout (float offsets) — live-range-checked (round-14 proven):
  u16*   QKVb  = (u16*)(ws + 0);
  u16*   xb    = (u16*)(ws + 6291456);
  u16*   Wqkvb = (u16*)(ws + 8388608);
  u16*   Wob   = (u16*)(ws + 9961472);
  u16*   w1b   = (u16*)(ws + 10485760);
  u16*   w2b   = (u16*)(ws + 12582912);
  u16*   Obf   = (u16*)(ws + 14680064);
  u16*   X1a   = (u16*)(ws + 16777216);
  u16*   X1c   = (u16*)(ws + 18874368);
  u16*   X2b   = (u16*)(ws + 20971520);
  u16*   X3a   = (u16*)(ws + 23068672);
  u16*   X3c   = (u16*)(ws + 25165824);
  u16*   Hb    = (u16*)(ws + 0);

  const dim3 blk(256);

  cvt_all<<<8192, blk, 0, stream>>>(x, Wq, Wk, Wv, Wo, w1, w2,
                                    xb, Wqkvb, Wob, w1b, w2b);

  // fused QKV projection: [4096,3072] = xb @ Wqkvb^T, bf16 out
  gemm_bf16<128, 128, false, false><<<dim3(3072 / 128, MROWS / 128), blk, 0, stream>>>(
      xb, Wqkvb, nullptr, QKVb, MROWS, 3072, DM, DM);

  // MFMA flash attention v5 -> Obf
  attn_mfma<<<dim3(SEQ / 128, BSZ * NH), dim3(512), 0, stream>>>(QKVb, mask, Obf);

  // X1 = O @ Wo^T, split-K x2 (partials X1a, X1c; summed in LN1)
  gemm_bf16<64, 128, false, false><<<dim3(DM / 128, MROWS / 64, 2), blk, 0, stream>>>(
      Obf, Wob, nullptr, X1a, MROWS, DM, DM / 2, DM);

  // X2 = LN(X1a + X1c + xb) -> bf16
  ln_add<true, true, false><<<dim3(MROWS), blk, 0, stream>>>(
      X1a, xb, X1c, nullptr, g1, be1, X2b);

  // H = relu(X2 @ w1^T + b1) -> bf16
  gemm_bf16<128, 128, true, true><<<dim3(DFF / 128, MROWS / 128), blk, 0, stream>>>(
      X2b, w1b, b1, Hb, MROWS, DFF, DM, DM);

  // X3 = H @ w2^T, split-K x2 (partials X3a, X3c; bias b2 added in LN2)
  gemm_bf16<64, 128, false, false><<<dim3(DM / 128, MROWS / 64, 2), blk, 0, stream>>>(
      Hb, w2b, nullptr, X3a, MROWS, DM, DFF / 2, DFF);

  // out = LN(X2 + X3a + X3c + b2) -> fp32
  ln_add<false, true, true><<<dim3(MROWS), blk, 0, stream>>>(
      X2b, X3a, X3c, b2, g2, be2, out);
}

// Round 17
// 259.762 us; speedup vs baseline: 1.0479x; 1.0090x over previous
//
#include <hip/hip_runtime.h>
#include <math.h>

typedef __attribute__((ext_vector_type(8))) short bf16x8;
typedef __attribute__((ext_vector_type(4))) float f32x4;
typedef __attribute__((ext_vector_type(8))) unsigned short us8;
typedef unsigned short u16;
typedef unsigned int u32;

constexpr int BSZ = 2, SEQ = 2048, DM = 1024, DFF = 4096, NH = 16, DH = 64;
constexpr int MROWS = BSZ * SEQ;  // 4096

__device__ __forceinline__ float bf2f(u16 u) {
  union { unsigned int i; float f; } v; v.i = ((unsigned int)u) << 16; return v.f;
}
__device__ __forceinline__ u16 f2bf(float f) {
  union { float f; unsigned int i; } v; v.f = f;
  unsigned int r = v.i + 0x7fffu + ((v.i >> 16) & 1u);
  return (u16)(r >> 16);
}
__device__ __forceinline__ float max3(float a, float b, float c) {
  float d;
  asm("v_max3_f32 %0, %1, %2, %3" : "=v"(d) : "v"(a), "v"(b), "v"(c));
  return d;
}

#define GLOAD16(gp, lp) __builtin_amdgcn_global_load_lds( \
    (const __attribute__((address_space(1))) void*)(gp),  \
    (__attribute__((address_space(3))) void*)(lp), 16, 0, 0)
#define GLOAD4(gp, lp) __builtin_amdgcn_global_load_lds( \
    (const __attribute__((address_space(1))) void*)(gp),  \
    (__attribute__((address_space(3))) void*)(lp), 4, 0, 0)

// ---------------------------------------------------------------------------
// Fused fp32 -> bf16 convert for ALL weights/activations (one launch).
// ---------------------------------------------------------------------------
__global__ __launch_bounds__(256) void cvt_all(
    const float* __restrict__ x, const float* __restrict__ Wq,
    const float* __restrict__ Wk, const float* __restrict__ Wv,
    const float* __restrict__ Wo, const float* __restrict__ w1,
    const float* __restrict__ w2, u16* __restrict__ xb,
    u16* __restrict__ Wqkvb, u16* __restrict__ Wob,
    u16* __restrict__ w1b, u16* __restrict__ w2b) {
  constexpr int M1 = 1 << 20;
  const int i = (blockIdx.x * 256 + threadIdx.x) * 8;
  const float* src;
  u16* dst;
  int off;
  if (i < 4 * M1)        { src = x;  dst = xb;            off = i;           }
  else if (i < 5 * M1)   { src = Wq; dst = Wqkvb;         off = i - 4 * M1;  }
  else if (i < 6 * M1)   { src = Wk; dst = Wqkvb + M1;    off = i - 5 * M1;  }
  else if (i < 7 * M1)   { src = Wv; dst = Wqkvb + 2 * M1; off = i - 6 * M1; }
  else if (i < 8 * M1)   { src = Wo; dst = Wob;           off = i - 7 * M1;  }
  else if (i < 12 * M1)  { src = w1; dst = w1b;           off = i - 8 * M1;  }
  else                   { src = w2; dst = w2b;           off = i - 12 * M1; }
  const float4 a = *(const float4*)(src + off);
  const float4 b = *(const float4*)(src + off + 4);
  uint4 o;
  o.x = f2bf(a.x) | ((unsigned)f2bf(a.y) << 16);
  o.y = f2bf(a.z) | ((unsigned)f2bf(a.w) << 16);
  o.z = f2bf(b.x) | ((unsigned)f2bf(b.y) << 16);
  o.w = f2bf(b.z) | ((unsigned)f2bf(b.w) << 16);
  *(uint4*)(dst + off) = o;
}

// ---------------------------------------------------------------------------
// bf16 MFMA GEMM, 2-phase double-buffered + XCD swizzle (+ split-K via z).
// ---------------------------------------------------------------------------
template <int BM, int BN, bool BIAS, bool RELU>
__global__ __launch_bounds__(256) void gemm_bf16(
    const u16* __restrict__ A, const u16* __restrict__ B,
    const float* __restrict__ bias, u16* __restrict__ Cb,
    int M, int N, int K, int ld) {
  constexpr int MI = BM / 32, NI = BN / 32;
  __shared__ u16 As[2][BM * 32];
  __shared__ u16 Bs[2][BN * 32];
  const int tid = threadIdx.x;
  const int lane = tid & 63, wid = tid >> 6;

  const int nwg = gridDim.x * gridDim.y;
  int id = blockIdx.y * gridDim.x + blockIdx.x;
  id = (id & 7) * (nwg >> 3) + (id >> 3);
  const int bx = id % gridDim.x, by = id / gridDim.x;

  const u16* Az = A + (size_t)blockIdx.z * K;
  const u16* Bz = B + (size_t)blockIdx.z * K;
  u16* Cz = Cb + (size_t)blockIdx.z * M * N;

  const int row0 = by * BM, col0 = bx * BN;
  const int wr = (wid >> 1) * (BM / 2), wc = (wid & 1) * (BN / 2);
  const int fr = lane & 15, hi = lane >> 4;

  f32x4 acc[MI][NI];
#pragma unroll
  for (int i = 0; i < MI; ++i)
#pragma unroll
    for (int j = 0; j < NI; ++j) acc[i][j] = {0.f, 0.f, 0.f, 0.f};

  const int sr = tid >> 2;
  const int se = (tid & 3) * 8;

#define STAGE(buf, k0)                                                        \
  {                                                                           \
    _Pragma("unroll")                                                         \
    for (int c = 0; c < BM * 64; c += 4096) {                                 \
      const int r = (c >> 6) + sr;                                            \
      GLOAD16(Az + (size_t)(row0 + r) * ld + ((k0) + se),                     \
              ((char*)As[buf]) + c + tid * 16);                               \
    }                                                                         \
    _Pragma("unroll")                                                         \
    for (int c = 0; c < BN * 64; c += 4096) {                                 \
      const int r = (c >> 6) + sr;                                            \
      GLOAD16(Bz + (size_t)(col0 + r) * ld + ((k0) + se),                     \
              ((char*)Bs[buf]) + c + tid * 16);                               \
    }                                                                         \
  }

  STAGE(0, 0);
  __syncthreads();

  const int NIT = K / 32;
  for (int it = 0; it < NIT; ++it) {
    const int cur = it & 1;
    if (it + 1 < NIT) STAGE(cur ^ 1, (it + 1) * 32);

    bf16x8 af[MI], bv[NI];
#pragma unroll
    for (int mi = 0; mi < MI; ++mi)
      af[mi] = *(const bf16x8*)&As[cur][(wr + mi * 16 + fr) * 32 + hi * 8];
#pragma unroll
    for (int ni = 0; ni < NI; ++ni)
      bv[ni] = *(const bf16x8*)&Bs[cur][(wc + ni * 16 + fr) * 32 + hi * 8];
#pragma unroll
    for (int mi = 0; mi < MI; ++mi)
#pragma unroll
      for (int ni = 0; ni < NI; ++ni)
        acc[mi][ni] = __builtin_amdgcn_mfma_f32_16x16x32_bf16(
            af[mi], bv[ni], acc[mi][ni], 0, 0, 0);
    __syncthreads();
  }
#undef STAGE

  const int erow = row0 + wr + (hi << 2);
  const int ecol0 = col0 + wc;
#pragma unroll
  for (int ni = 0; ni < NI; ++ni) {
    const int col = ecol0 + ni * 16 + fr;
    const float bvv = BIAS ? bias[col] : 0.f;
#pragma unroll
    for (int mi = 0; mi < MI; ++mi) {
      const int rbase = erow + mi * 16;
#pragma unroll
      for (int j = 0; j < 4; ++j) {
        float v = acc[mi][ni][j] + bvv;
        if (RELU) v = fmaxf(v, 0.f);
        Cz[(size_t)(rbase + j) * N + col] = f2bf(v);
      }
    }
  }
}

// ---------------------------------------------------------------------------
// MFMA flash attention v8 = v5 + wave-uniform mask fast path + v_max3 rmax.
// 512 thr = 8 waves, QB=128, KB=64. Pipe-throughput-bound (r15): do not
// re-split; cuts here must reduce per-iter VALU/LDS issue.
// ---------------------------------------------------------------------------
__global__ __launch_bounds__(512) void attn_mfma(
    const u16* __restrict__ QKV, const int* __restrict__ mask,
    u16* __restrict__ Ob) {
  constexpr int KB = 64, QB = 128, NT = SEQ / KB;
  __shared__ u16 Kl[2][KB * 64];
  __shared__ u16 Vt[2][64 * KB];
  __shared__ int ml[2][KB];

  const int tid = threadIdx.x;
  const int lane = tid & 63, wid = tid >> 6;
  const int q0 = blockIdx.x * QB;
  const int bh = blockIdx.y;
  const int b = bh >> 4, h = bh & 15;
  const size_t base = (size_t)b * SEQ * 3072;
  const int fr = lane & 15, g = lane >> 4;

  const u16* qp = QKV + base + (size_t)(q0 + wid * 16 + fr) * 3072 + h * 64 + g * 8;
  bf16x8 qf0, qf1;
  {
    const float QSC = 0.18033688f;  // 0.125 * log2(e)
    const us8 ua = *(const us8*)qp;
    const us8 ub = *(const us8*)(qp + 32);
    u32 pa[4], pb[4];
#pragma unroll
    for (int i = 0; i < 4; ++i) {
      const float a0 = bf2f(ua[2 * i]) * QSC, a1 = bf2f(ua[2 * i + 1]) * QSC;
      const float b0 = bf2f(ub[2 * i]) * QSC, b1 = bf2f(ub[2 * i + 1]) * QSC;
      asm("v_cvt_pk_bf16_f32 %0, %1, %2" : "=v"(pa[i]) : "v"(a0), "v"(a1));
      asm("v_cvt_pk_bf16_f32 %0, %1, %2" : "=v"(pb[i]) : "v"(b0), "v"(b1));
    }
    union { u32 d[4]; bf16x8 v; } c0, c1;
#pragma unroll
    for (int i = 0; i < 4; ++i) { c0.d[i] = pa[i]; c1.d[i] = pb[i]; }
    qf0 = c0.v; qf1 = c1.v;
  }

  const int krow = wid * 8 + (lane >> 3);
  const int kcol = 8 * ((lane & 7) ^ (lane >> 3));
  const u16* ksrc = QKV + base + 1024 + h * 64 + kcol;
  const int kdst = wid * 1024 + lane * 16;

  const int va = (tid & 255) >> 3;
  const int vq = tid & 7;
  const u16* vsrc = QKV + base + 2048 + h * 64 + vq * 8;
  const bool vstage = (wid < 4);

  f32x4 o[4] = {{0.f,0.f,0.f,0.f},{0.f,0.f,0.f,0.f},{0.f,0.f,0.f,0.f},{0.f,0.f,0.f,0.f}};
  float mreg = -3e38f, lreg = 0.f;

  {
    GLOAD16(ksrc + (size_t)krow * 3072, (char*)Kl[0] + kdst);
    if (wid == 4) GLOAD4(mask + b * SEQ + lane, (char*)ml[0] + lane * 4);
    if (vstage) {
      const us8 v0 = *(const us8*)(vsrc + (size_t)(2 * va) * 3072);
      const us8 v1 = *(const us8*)(vsrc + (size_t)(2 * va + 1) * 3072);
      char* vb = (char*)Vt[0];
#pragma unroll
      for (int i = 0; i < 8; ++i) {
        const int d = vq * 8 + i;
        const u32 wv = (u32)(u16)v0[i] | ((u32)(u16)v1[i] << 16);
        *(u32*)(vb + d * 128 + ((4 * va) ^ ((vq ^ i) << 4))) = wv;
      }
    }
  }
  __syncthreads();

  for (int it = 0; it < NT; ++it) {
    const int cur = it & 1, nxt = cur ^ 1;
    const int ktn = (it + 1) * KB;
    const bool pre = (it + 1 < NT);
    us8 v0 = {}, v1 = {};
    if (pre) {
      GLOAD16(ksrc + (size_t)(ktn + krow) * 3072, (char*)Kl[nxt] + kdst);
      if (wid == 4) GLOAD4(mask + b * SEQ + ktn + lane, (char*)ml[nxt] + lane * 4);
      if (vstage) {
        v0 = *(const us8*)(vsrc + (size_t)(ktn + 2 * va) * 3072);
        v1 = *(const us8*)(vsrc + (size_t)(ktn + 2 * va + 1) * 3072);
      }
    }

    f32x4 s[4];
#pragma unroll
    for (int t16 = 0; t16 < 4; ++t16) {
      const int kr = t16 * 16 + fr;
      const char* krp = (const char*)Kl[cur] + kr * 128;
      const int sw = (kr & 7) << 4;
      const bf16x8 kf0 = *(const bf16x8*)(krp + ((g * 16) ^ sw));
      const bf16x8 kf1 = *(const bf16x8*)(krp + ((g * 16 + 64) ^ sw));
      f32x4 a = {0.f, 0.f, 0.f, 0.f};
      a = __builtin_amdgcn_mfma_f32_16x16x32_bf16(kf0, qf0, a, 0, 0, 0);
      a = __builtin_amdgcn_mfma_f32_16x16x32_bf16(kf1, qf1, a, 0, 0, 0);
      s[t16] = a;
    }

    // ---- mask: wave-uniform fast path (common case: all-ones tile)
    if (!__all(ml[cur][lane] != 0)) {
#pragma unroll
      for (int t16 = 0; t16 < 4; ++t16) {
        const int4 mv = *(const int4*)&ml[cur][t16 * 16 + g * 4];
        const int* mp = (const int*)&mv;
#pragma unroll
        for (int j = 0; j < 4; ++j)
          if (mp[j] == 0) s[t16][j] = -3e38f;
      }
    }

    // ---- per-lane rmax via v_max3 tree (exact, 8 ops)
    const float m1 = max3(s[0][0], s[0][1], s[0][2]);
    const float m2 = max3(s[0][3], s[1][0], s[1][1]);
    const float m3 = max3(s[1][2], s[1][3], s[2][0]);
    const float m4 = max3(s[2][1], s[2][2], s[2][3]);
    const float m5 = max3(s[3][0], s[3][1], s[3][2]);
    float rmax = fmaxf(max3(m1, m2, m3), max3(m4, m5, s[3][3]));

    if (!__all(rmax <= mreg + 12.f)) {
      rmax = fmaxf(rmax, __shfl_xor(rmax, 16));
      rmax = fmaxf(rmax, __shfl_xor(rmax, 32));
      const float mn = fmaxf(mreg, rmax);
      float sc;
      asm("v_exp_f32 %0, %1" : "=v"(sc) : "v"(mreg - mn));
      mreg = mn;
      lreg *= sc;
#pragma unroll
      for (int j = 0; j < 4; ++j) {
        const float scj = __shfl(sc, (g << 4) + g * 4 + j);
#pragma unroll
        for (int dt = 0; dt < 4; ++dt) o[dt][j] *= scj;
      }
    }

    float p[4][4];
#pragma unroll
    for (int t16 = 0; t16 < 4; ++t16)
#pragma unroll
      for (int j = 0; j < 4; ++j) {
        float e;
        asm("v_exp_f32 %0, %1" : "=v"(e) : "v"(s[t16][j] - mreg));
        p[t16][j] = e;
        lreg += e;
      }

    u32 plo[4], phi[4];
#pragma unroll
    for (int t16 = 0; t16 < 4; ++t16) {
      asm("v_cvt_pk_bf16_f32 %0, %1, %2"
          : "=v"(plo[t16]) : "v"(p[t16][0]), "v"(p[t16][1]));
      asm("v_cvt_pk_bf16_f32 %0, %1, %2"
          : "=v"(phi[t16]) : "v"(p[t16][2]), "v"(p[t16][3]));
    }

#pragma unroll
    for (int kh = 0; kh < 2; ++kh) {
      u32 fd[4];
#pragma unroll
      for (int hf = 0; hf < 2; ++hf) {
        const int sl = fr + ((((g & 1) << 1) + hf) << 4);
        const u32 c0l = (u32)__shfl((int)plo[kh * 2], sl);
        const u32 c0h = (u32)__shfl((int)phi[kh * 2], sl);
        const u32 c1l = (u32)__shfl((int)plo[kh * 2 + 1], sl);
        const u32 c1h = (u32)__shfl((int)phi[kh * 2 + 1], sl);
        const bool s1 = ((g >> 1) & 1) != 0;
        fd[hf * 2] = s1 ? c1l : c0l;
        fd[hf * 2 + 1] = s1 ? c1h : c0h;
      }
      union { u32 d[4]; bf16x8 v; } uu;
      uu.d[0] = fd[0]; uu.d[1] = fd[1]; uu.d[2] = fd[2]; uu.d[3] = fd[3];
      const bf16x8 pf = uu.v;
#pragma unroll
      for (int dt = 0; dt < 4; ++dt) {
        const int d = dt * 16 + fr;
        const int xd = (((d >> 3) ^ d) & 7) << 4;
        const bf16x8 vf = *(const bf16x8*)((const char*)Vt[cur] + d * 128 +
                                           ((g * 16 + kh * 64) ^ xd));
        o[dt] = __builtin_amdgcn_mfma_f32_16x16x32_bf16(pf, vf, o[dt], 0, 0, 0);
      }
    }

    if (pre && vstage) {
      char* vb = (char*)Vt[nxt];
#pragma unroll
      for (int i = 0; i < 8; ++i) {
        const int d = vq * 8 + i;
        const u32 wv = (u32)(u16)v0[i] | ((u32)(u16)v1[i] << 16);
        *(u32*)(vb + d * 128 + ((4 * va) ^ ((vq ^ i) << 4))) = wv;
      }
    }
    __syncthreads();
  }

  lreg += __shfl_xor(lreg, 16);
  lreg += __shfl_xor(lreg, 32);
  const float inv = 1.f / lreg;
#pragma unroll
  for (int j = 0; j < 4; ++j) {
    const float invj = __shfl(inv, (g << 4) + g * 4 + j);
    const int qrow = q0 + wid * 16 + g * 4 + j;
    u16* orow = Ob + (size_t)(b * SEQ + qrow) * DM + h * 64;
#pragma unroll
    for (int dt = 0; dt < 4; ++dt)
      orow[dt * 16 + fr] = f2bf(o[dt][j] * invj);
  }
}

// ---------------------------------------------------------------------------
// Fused residual-add + LayerNorm with up to 3 bf16 addends + optional bias.
// ---------------------------------------------------------------------------
template <bool OBF, bool HASC, bool HASB>
__global__ __launch_bounds__(256) void ln_add(
    const u16* __restrict__ Ap, const u16* __restrict__ Bp,
    const u16* __restrict__ Cp, const float* __restrict__ bias,
    const float* __restrict__ g, const float* __restrict__ be,
    void* __restrict__ outp) {
  __shared__ float red[2][4];
  __shared__ float mu_s, sig_s;
  const int row = blockIdx.x;
  const int tid = threadIdx.x;
  const size_t off = (size_t)row * DM + tid * 4;

  const ushort4 ua = *(const ushort4*)(Ap + off);
  const ushort4 ub = *(const ushort4*)(Bp + off);
  float4 s = make_float4(bf2f(ua.x) + bf2f(ub.x), bf2f(ua.y) + bf2f(ub.y),
                         bf2f(ua.z) + bf2f(ub.z), bf2f(ua.w) + bf2f(ub.w));
  if (HASC) {
    const ushort4 uc = *(const ushort4*)(Cp + off);
    s.x += bf2f(uc.x); s.y += bf2f(uc.y); s.z += bf2f(uc.z); s.w += bf2f(uc.w);
  }
  if (HASB) {
    const float4 bb = *(const float4*)(bias + tid * 4);
    s.x += bb.x; s.y += bb.y; s.z += bb.z; s.w += bb.w;
  }

  float sum = s.x + s.y + s.z + s.w;
  float sq = s.x * s.x + s.y * s.y + s.z * s.z + s.w * s.w;
#pragma unroll
  for (int off2 = 32; off2 >= 1; off2 >>= 1) {
    sum += __shfl_xor(sum, off2);
    sq += __shfl_xor(sq, off2);
  }
  const int wid = tid >> 6;
  if ((tid & 63) == 0) { red[0][wid] = sum; red[1][wid] = sq; }
  __syncthreads();
  if (tid == 0) {
    float ts = red[0][0] + red[0][1] + red[0][2] + red[0][3];
    float tq = red[1][0] + red[1][1] + red[1][2] + red[1][3];
    float mu = ts * (1.f / DM);
    float var = tq * (1.f / DM) - mu * mu;
    mu_s = mu;
    sig_s = sqrtf(fmaxf(var, 0.f)) + 1e-6f;
  }
  __syncthreads();
  const float mu = mu_s, inv = 1.f / sig_s;
  const float4 gv = *(const float4*)(g + tid * 4);
  const float4 bv = *(const float4*)(be + tid * 4);
  float4 o;
  o.x = (s.x - mu) * inv * gv.x + bv.x;
  o.y = (s.y - mu) * inv * gv.y + bv.y;
  o.z = (s.z - mu) * inv * gv.z + bv.z;
  o.w = (s.w - mu) * inv * gv.w + bv.w;
  if (OBF) {
    u16* op = (u16*)outp + off;
    ushort4 o4;
    o4.x = f2bf(o.x); o4.y = f2bf(o.y); o4.z = f2bf(o.z); o4.w = f2bf(o.w);
    *(ushort4*)op = o4;
  } else {
    *(float4*)((float*)outp + off) = o;
  }
}

// ---------------------------------------------------------------------------
extern "C" void kernel_launch(void* const* d_in, const int* in_sizes, int n_in,
                              void* d_out, int out_size, void* d_ws,
                              size_t ws_size, hipStream_t stream) {
  const float* x  = (const float*)d_in[0];
  const int* mask = (const int*)d_in[1];
  const float* Wq = (const float*)d_in[2];
  const float* Wk = (const float*)d_in[3];
  const float* Wv = (const float*)d_in[4];
  const float* Wo = (const float*)d_in[5];
  const float* w1 = (const float*)d_in[6];
  const float* b1 = (const float*)d_in[7];
  const float* w2 = (const float*)d_in[8];
  const float* b2 = (const float*)d_in[9];
  const float* g1 = (const float*)d_in[10];
  const float* be1 = (const float*)d_in[11];
  const float* g2 = (const float*)d_in[12];
  const float* be2 = (const float*)d_in[13];
  float* out = (float*)d_out;
  float* ws = (float*)d_ws;

  // workspace layout (float offsets) — live-range-checked (round-14 proven):
  u16*   QKVb  = (u16*)(ws + 0);
  u16*   xb    = (u16*)(ws + 6291456);
  u16*   Wqkvb = (u16*)(ws + 8388608);
  u16*   Wob   = (u16*)(ws + 9961472);
  u16*   w1b   = (u16*)(ws + 10485760);
  u16*   w2b   = (u16*)(ws + 12582912);
  u16*   Obf   = (u16*)(ws + 14680064);
  u16*   X1a   = (u16*)(ws + 16777216);
  u16*   X1c   = (u16*)(ws + 18874368);
  u16*   X2b   = (u16*)(ws + 20971520);
  u16*   X3a   = (u16*)(ws + 23068672);
  u16*   X3c   = (u16*)(ws + 25165824);
  u16*   Hb    = (u16*)(ws + 0);

  const dim3 blk(256);

  cvt_all<<<8192, blk, 0, stream>>>(x, Wq, Wk, Wv, Wo, w1, w2,
                                    xb, Wqkvb, Wob, w1b, w2b);

  // fused QKV projection: [4096,3072] = xb @ Wqkvb^T, bf16 out
  gemm_bf16<128, 128, false, false><<<dim3(3072 / 128, MROWS / 128), blk, 0, stream>>>(
      xb, Wqkvb, nullptr, QKVb, MROWS, 3072, DM, DM);

  // MFMA flash attention v8 -> Obf
  attn_mfma<<<dim3(SEQ / 128, BSZ * NH), dim3(512), 0, stream>>>(QKVb, mask, Obf);

  // X1 = O @ Wo^T, split-K x2 (partials X1a, X1c; summed in LN1)
  gemm_bf16<64, 128, false, false><<<dim3(DM / 128, MROWS / 64, 2), blk, 0, stream>>>(
      Obf, Wob, nullptr, X1a, MROWS, DM, DM / 2, DM);

  // X2 = LN(X1a + X1c + xb) -> bf16
  ln_add<true, true, false><<<dim3(MROWS), blk, 0, stream>>>(
      X1a, xb, X1c, nullptr, g1, be1, X2b);

  // H = relu(X2 @ w1^T + b1) -> bf16
  gemm_bf16<128, 128, true, true><<<dim3(DFF / 128, MROWS / 128), blk, 0, stream>>>(
      X2b, w1b, b1, Hb, MROWS, DFF, DM, DM);

  // X3 = H @ w2^T, split-K x2 (partials X3a, X3c; bias b2 added in LN2)
  gemm_bf16<64, 128, false, false><<<dim3(DM / 128, MROWS / 64, 2), blk, 0, stream>>>(
      Hb, w2b, nullptr, X3a, MROWS, DM, DFF / 2, DFF);

  // out = LN(X2 + X3a + X3c + b2) -> fp32
  ln_add<false, true, true><<<dim3(MROWS), blk, 0, stream>>>(
      X2b, X3a, X3c, b2, g2, be2, out);
}

// Round 18
// 258.304 us; speedup vs baseline: 1.0538x; 1.0056x over previous
//
#include <hip/hip_runtime.h>
#include <math.h>

typedef __attribute__((ext_vector_type(8))) short bf16x8;
typedef __attribute__((ext_vector_type(4))) float f32x4;
typedef __attribute__((ext_vector_type(8))) unsigned short us8;
typedef unsigned short u16;
typedef unsigned int u32;

constexpr int BSZ = 2, SEQ = 2048, DM = 1024, DFF = 4096, NH = 16, DH = 64;
constexpr int MROWS = BSZ * SEQ;  // 4096

__device__ __forceinline__ float bf2f(u16 u) {
  union { unsigned int i; float f; } v; v.i = ((unsigned int)u) << 16; return v.f;
}
__device__ __forceinline__ u16 f2bf(float f) {
  union { float f; unsigned int i; } v; v.f = f;
  unsigned int r = v.i + 0x7fffu + ((v.i >> 16) & 1u);
  return (u16)(r >> 16);
}
__device__ __forceinline__ float max3(float a, float b, float c) {
  float d;
  asm("v_max3_f32 %0, %1, %2, %3" : "=v"(d) : "v"(a), "v"(b), "v"(c));
  return d;
}

#define GLOAD16(gp, lp) __builtin_amdgcn_global_load_lds( \
    (const __attribute__((address_space(1))) void*)(gp),  \
    (__attribute__((address_space(3))) void*)(lp), 16, 0, 0)
#define GLOAD4(gp, lp) __builtin_amdgcn_global_load_lds( \
    (const __attribute__((address_space(1))) void*)(gp),  \
    (__attribute__((address_space(3))) void*)(lp), 4, 0, 0)

// ---------------------------------------------------------------------------
// Fused fp32 -> bf16 convert for ALL weights/activations (one launch).
// ---------------------------------------------------------------------------
__global__ __launch_bounds__(256) void cvt_all(
    const float* __restrict__ x, const float* __restrict__ Wq,
    const float* __restrict__ Wk, const float* __restrict__ Wv,
    const float* __restrict__ Wo, const float* __restrict__ w1,
    const float* __restrict__ w2, u16* __restrict__ xb,
    u16* __restrict__ Wqkvb, u16* __restrict__ Wob,
    u16* __restrict__ w1b, u16* __restrict__ w2b) {
  constexpr int M1 = 1 << 20;
  const int i = (blockIdx.x * 256 + threadIdx.x) * 8;
  const float* src;
  u16* dst;
  int off;
  if (i < 4 * M1)        { src = x;  dst = xb;            off = i;           }
  else if (i < 5 * M1)   { src = Wq; dst = Wqkvb;         off = i - 4 * M1;  }
  else if (i < 6 * M1)   { src = Wk; dst = Wqkvb + M1;    off = i - 5 * M1;  }
  else if (i < 7 * M1)   { src = Wv; dst = Wqkvb + 2 * M1; off = i - 6 * M1; }
  else if (i < 8 * M1)   { src = Wo; dst = Wob;           off = i - 7 * M1;  }
  else if (i < 12 * M1)  { src = w1; dst = w1b;           off = i - 8 * M1;  }
  else                   { src = w2; dst = w2b;           off = i - 12 * M1; }
  const float4 a = *(const float4*)(src + off);
  const float4 b = *(const float4*)(src + off + 4);
  uint4 o;
  o.x = f2bf(a.x) | ((unsigned)f2bf(a.y) << 16);
  o.y = f2bf(a.z) | ((unsigned)f2bf(a.w) << 16);
  o.z = f2bf(b.x) | ((unsigned)f2bf(b.y) << 16);
  o.w = f2bf(b.z) | ((unsigned)f2bf(b.w) << 16);
  *(uint4*)(dst + off) = o;
}

// ---------------------------------------------------------------------------
// bf16 MFMA GEMM, 2-phase double-buffered + XCD swizzle (+ split-K via z).
// ---------------------------------------------------------------------------
template <int BM, int BN, bool BIAS, bool RELU>
__global__ __launch_bounds__(256) void gemm_bf16(
    const u16* __restrict__ A, const u16* __restrict__ B,
    const float* __restrict__ bias, u16* __restrict__ Cb,
    int M, int N, int K, int ld) {
  constexpr int MI = BM / 32, NI = BN / 32;
  __shared__ u16 As[2][BM * 32];
  __shared__ u16 Bs[2][BN * 32];
  const int tid = threadIdx.x;
  const int lane = tid & 63, wid = tid >> 6;

  const int nwg = gridDim.x * gridDim.y;
  int id = blockIdx.y * gridDim.x + blockIdx.x;
  id = (id & 7) * (nwg >> 3) + (id >> 3);
  const int bx = id % gridDim.x, by = id / gridDim.x;

  const u16* Az = A + (size_t)blockIdx.z * K;
  const u16* Bz = B + (size_t)blockIdx.z * K;
  u16* Cz = Cb + (size_t)blockIdx.z * M * N;

  const int row0 = by * BM, col0 = bx * BN;
  const int wr = (wid >> 1) * (BM / 2), wc = (wid & 1) * (BN / 2);
  const int fr = lane & 15, hi = lane >> 4;

  f32x4 acc[MI][NI];
#pragma unroll
  for (int i = 0; i < MI; ++i)
#pragma unroll
    for (int j = 0; j < NI; ++j) acc[i][j] = {0.f, 0.f, 0.f, 0.f};

  const int sr = tid >> 2;
  const int se = (tid & 3) * 8;

#define STAGE(buf, k0)                                                        \
  {                                                                           \
    _Pragma("unroll")                                                         \
    for (int c = 0; c < BM * 64; c += 4096) {                                 \
      const int r = (c >> 6) + sr;                                            \
      GLOAD16(Az + (size_t)(row0 + r) * ld + ((k0) + se),                     \
              ((char*)As[buf]) + c + tid * 16);                               \
    }                                                                         \
    _Pragma("unroll")                                                         \
    for (int c = 0; c < BN * 64; c += 4096) {                                 \
      const int r = (c >> 6) + sr;                                            \
      GLOAD16(Bz + (size_t)(col0 + r) * ld + ((k0) + se),                     \
              ((char*)Bs[buf]) + c + tid * 16);                               \
    }                                                                         \
  }

  STAGE(0, 0);
  __syncthreads();

  const int NIT = K / 32;
  for (int it = 0; it < NIT; ++it) {
    const int cur = it & 1;
    if (it + 1 < NIT) STAGE(cur ^ 1, (it + 1) * 32);

    bf16x8 af[MI], bv[NI];
#pragma unroll
    for (int mi = 0; mi < MI; ++mi)
      af[mi] = *(const bf16x8*)&As[cur][(wr + mi * 16 + fr) * 32 + hi * 8];
#pragma unroll
    for (int ni = 0; ni < NI; ++ni)
      bv[ni] = *(const bf16x8*)&Bs[cur][(wc + ni * 16 + fr) * 32 + hi * 8];
#pragma unroll
    for (int mi = 0; mi < MI; ++mi)
#pragma unroll
      for (int ni = 0; ni < NI; ++ni)
        acc[mi][ni] = __builtin_amdgcn_mfma_f32_16x16x32_bf16(
            af[mi], bv[ni], acc[mi][ni], 0, 0, 0);
    __syncthreads();
  }
#undef STAGE

  const int erow = row0 + wr + (hi << 2);
  const int ecol0 = col0 + wc;
#pragma unroll
  for (int ni = 0; ni < NI; ++ni) {
    const int col = ecol0 + ni * 16 + fr;
    const float bvv = BIAS ? bias[col] : 0.f;
#pragma unroll
    for (int mi = 0; mi < MI; ++mi) {
      const int rbase = erow + mi * 16;
#pragma unroll
      for (int j = 0; j < 4; ++j) {
        float v = acc[mi][ni][j] + bvv;
        if (RELU) v = fmaxf(v, 0.f);
        Cz[(size_t)(rbase + j) * N + col] = f2bf(v);
      }
    }
  }
}

// ---------------------------------------------------------------------------
// MFMA flash attention v9 = v8 + block-level mask-uniform hoist: the full
// mask is read once in the prologue; if all-ones (block-uniform SGPR flag),
// all per-iter mask staging/reads/ballots are skipped. Exact fallback kept.
// ---------------------------------------------------------------------------
__global__ __launch_bounds__(512) void attn_mfma(
    const u16* __restrict__ QKV, const int* __restrict__ mask,
    u16* __restrict__ Ob) {
  constexpr int KB = 64, QB = 128, NT = SEQ / KB;
  __shared__ u16 Kl[2][KB * 64];
  __shared__ u16 Vt[2][64 * KB];
  __shared__ int ml[2][KB];

  const int tid = threadIdx.x;
  const int lane = tid & 63, wid = tid >> 6;
  const int q0 = blockIdx.x * QB;
  const int bh = blockIdx.y;
  const int b = bh >> 4, h = bh & 15;
  const size_t base = (size_t)b * SEQ * 3072;
  const int fr = lane & 15, g = lane >> 4;

  // ---- prologue: is this batch's mask entirely nonzero? (block-uniform)
  const int4 mchk = *(const int4*)(mask + b * SEQ + tid * 4);
  const bool mall = __syncthreads_and(
      (mchk.x != 0) && (mchk.y != 0) && (mchk.z != 0) && (mchk.w != 0));

  const u16* qp = QKV + base + (size_t)(q0 + wid * 16 + fr) * 3072 + h * 64 + g * 8;
  bf16x8 qf0, qf1;
  {
    const float QSC = 0.18033688f;  // 0.125 * log2(e)
    const us8 ua = *(const us8*)qp;
    const us8 ub = *(const us8*)(qp + 32);
    u32 pa[4], pb[4];
#pragma unroll
    for (int i = 0; i < 4; ++i) {
      const float a0 = bf2f(ua[2 * i]) * QSC, a1 = bf2f(ua[2 * i + 1]) * QSC;
      const float b0 = bf2f(ub[2 * i]) * QSC, b1 = bf2f(ub[2 * i + 1]) * QSC;
      asm("v_cvt_pk_bf16_f32 %0, %1, %2" : "=v"(pa[i]) : "v"(a0), "v"(a1));
      asm("v_cvt_pk_bf16_f32 %0, %1, %2" : "=v"(pb[i]) : "v"(b0), "v"(b1));
    }
    union { u32 d[4]; bf16x8 v; } c0, c1;
#pragma unroll
    for (int i = 0; i < 4; ++i) { c0.d[i] = pa[i]; c1.d[i] = pb[i]; }
    qf0 = c0.v; qf1 = c1.v;
  }

  const int krow = wid * 8 + (lane >> 3);
  const int kcol = 8 * ((lane & 7) ^ (lane >> 3));
  const u16* ksrc = QKV + base + 1024 + h * 64 + kcol;
  const int kdst = wid * 1024 + lane * 16;

  const int va = (tid & 255) >> 3;
  const int vq = tid & 7;
  const u16* vsrc = QKV + base + 2048 + h * 64 + vq * 8;
  const bool vstage = (wid < 4);

  f32x4 o[4] = {{0.f,0.f,0.f,0.f},{0.f,0.f,0.f,0.f},{0.f,0.f,0.f,0.f},{0.f,0.f,0.f,0.f}};
  float mreg = -3e38f, lreg = 0.f;

  {
    GLOAD16(ksrc + (size_t)krow * 3072, (char*)Kl[0] + kdst);
    if (!mall && wid == 4) GLOAD4(mask + b * SEQ + lane, (char*)ml[0] + lane * 4);
    if (vstage) {
      const us8 v0 = *(const us8*)(vsrc + (size_t)(2 * va) * 3072);
      const us8 v1 = *(const us8*)(vsrc + (size_t)(2 * va + 1) * 3072);
      char* vb = (char*)Vt[0];
#pragma unroll
      for (int i = 0; i < 8; ++i) {
        const int d = vq * 8 + i;
        const u32 wv = (u32)(u16)v0[i] | ((u32)(u16)v1[i] << 16);
        *(u32*)(vb + d * 128 + ((4 * va) ^ ((vq ^ i) << 4))) = wv;
      }
    }
  }
  __syncthreads();

  for (int it = 0; it < NT; ++it) {
    const int cur = it & 1, nxt = cur ^ 1;
    const int ktn = (it + 1) * KB;
    const bool pre = (it + 1 < NT);
    us8 v0 = {}, v1 = {};
    if (pre) {
      GLOAD16(ksrc + (size_t)(ktn + krow) * 3072, (char*)Kl[nxt] + kdst);
      if (!mall && wid == 4) GLOAD4(mask + b * SEQ + ktn + lane, (char*)ml[nxt] + lane * 4);
      if (vstage) {
        v0 = *(const us8*)(vsrc + (size_t)(ktn + 2 * va) * 3072);
        v1 = *(const us8*)(vsrc + (size_t)(ktn + 2 * va + 1) * 3072);
      }
    }

    f32x4 s[4];
#pragma unroll
    for (int t16 = 0; t16 < 4; ++t16) {
      const int kr = t16 * 16 + fr;
      const char* krp = (const char*)Kl[cur] + kr * 128;
      const int sw = (kr & 7) << 4;
      const bf16x8 kf0 = *(const bf16x8*)(krp + ((g * 16) ^ sw));
      const bf16x8 kf1 = *(const bf16x8*)(krp + ((g * 16 + 64) ^ sw));
      f32x4 a = {0.f, 0.f, 0.f, 0.f};
      a = __builtin_amdgcn_mfma_f32_16x16x32_bf16(kf0, qf0, a, 0, 0, 0);
      a = __builtin_amdgcn_mfma_f32_16x16x32_bf16(kf1, qf1, a, 0, 0, 0);
      s[t16] = a;
    }

    // ---- mask: fully hoisted when block-uniform all-ones
    if (!mall) {
      if (!__all(ml[cur][lane] != 0)) {
#pragma unroll
        for (int t16 = 0; t16 < 4; ++t16) {
          const int4 mv = *(const int4*)&ml[cur][t16 * 16 + g * 4];
          const int* mp = (const int*)&mv;
#pragma unroll
          for (int j = 0; j < 4; ++j)
            if (mp[j] == 0) s[t16][j] = -3e38f;
        }
      }
    }

    // ---- per-lane rmax via v_max3 tree (exact, 8 ops)
    const float m1 = max3(s[0][0], s[0][1], s[0][2]);
    const float m2 = max3(s[0][3], s[1][0], s[1][1]);
    const float m3 = max3(s[1][2], s[1][3], s[2][0]);
    const float m4 = max3(s[2][1], s[2][2], s[2][3]);
    const float m5 = max3(s[3][0], s[3][1], s[3][2]);
    float rmax = fmaxf(max3(m1, m2, m3), max3(m4, m5, s[3][3]));

    if (!__all(rmax <= mreg + 12.f)) {
      rmax = fmaxf(rmax, __shfl_xor(rmax, 16));
      rmax = fmaxf(rmax, __shfl_xor(rmax, 32));
      const float mn = fmaxf(mreg, rmax);
      float sc;
      asm("v_exp_f32 %0, %1" : "=v"(sc) : "v"(mreg - mn));
      mreg = mn;
      lreg *= sc;
#pragma unroll
      for (int j = 0; j < 4; ++j) {
        const float scj = __shfl(sc, (g << 4) + g * 4 + j);
#pragma unroll
        for (int dt = 0; dt < 4; ++dt) o[dt][j] *= scj;
      }
    }

    float p[4][4];
#pragma unroll
    for (int t16 = 0; t16 < 4; ++t16)
#pragma unroll
      for (int j = 0; j < 4; ++j) {
        float e;
        asm("v_exp_f32 %0, %1" : "=v"(e) : "v"(s[t16][j] - mreg));
        p[t16][j] = e;
        lreg += e;
      }

    u32 plo[4], phi[4];
#pragma unroll
    for (int t16 = 0; t16 < 4; ++t16) {
      asm("v_cvt_pk_bf16_f32 %0, %1, %2"
          : "=v"(plo[t16]) : "v"(p[t16][0]), "v"(p[t16][1]));
      asm("v_cvt_pk_bf16_f32 %0, %1, %2"
          : "=v"(phi[t16]) : "v"(p[t16][2]), "v"(p[t16][3]));
    }

#pragma unroll
    for (int kh = 0; kh < 2; ++kh) {
      u32 fd[4];
#pragma unroll
      for (int hf = 0; hf < 2; ++hf) {
        const int sl = fr + ((((g & 1) << 1) + hf) << 4);
        const u32 c0l = (u32)__shfl((int)plo[kh * 2], sl);
        const u32 c0h = (u32)__shfl((int)phi[kh * 2], sl);
        const u32 c1l = (u32)__shfl((int)plo[kh * 2 + 1], sl);
        const u32 c1h = (u32)__shfl((int)phi[kh * 2 + 1], sl);
        const bool s1 = ((g >> 1) & 1) != 0;
        fd[hf * 2] = s1 ? c1l : c0l;
        fd[hf * 2 + 1] = s1 ? c1h : c0h;
      }
      union { u32 d[4]; bf16x8 v; } uu;
      uu.d[0] = fd[0]; uu.d[1] = fd[1]; uu.d[2] = fd[2]; uu.d[3] = fd[3];
      const bf16x8 pf = uu.v;
#pragma unroll
      for (int dt = 0; dt < 4; ++dt) {
        const int d = dt * 16 + fr;
        const int xd = (((d >> 3) ^ d) & 7) << 4;
        const bf16x8 vf = *(const bf16x8*)((const char*)Vt[cur] + d * 128 +
                                           ((g * 16 + kh * 64) ^ xd));
        o[dt] = __builtin_amdgcn_mfma_f32_16x16x32_bf16(pf, vf, o[dt], 0, 0, 0);
      }
    }

    if (pre && vstage) {
      char* vb = (char*)Vt[nxt];
#pragma unroll
      for (int i = 0; i < 8; ++i) {
        const int d = vq * 8 + i;
        const u32 wv = (u32)(u16)v0[i] | ((u32)(u16)v1[i] << 16);
        *(u32*)(vb + d * 128 + ((4 * va) ^ ((vq ^ i) << 4))) = wv;
      }
    }
    __syncthreads();
  }

  lreg += __shfl_xor(lreg, 16);
  lreg += __shfl_xor(lreg, 32);
  const float inv = 1.f / lreg;
#pragma unroll
  for (int j = 0; j < 4; ++j) {
    const float invj = __shfl(inv, (g << 4) + g * 4 + j);
    const int qrow = q0 + wid * 16 + g * 4 + j;
    u16* orow = Ob + (size_t)(b * SEQ + qrow) * DM + h * 64;
#pragma unroll
    for (int dt = 0; dt < 4; ++dt)
      orow[dt * 16 + fr] = f2bf(o[dt][j] * invj);
  }
}

// ---------------------------------------------------------------------------
// Fused residual-add + LayerNorm with up to 3 bf16 addends + optional bias.
// ---------------------------------------------------------------------------
template <bool OBF, bool HASC, bool HASB>
__global__ __launch_bounds__(256) void ln_add(
    const u16* __restrict__ Ap, const u16* __restrict__ Bp,
    const u16* __restrict__ Cp, const float* __restrict__ bias,
    const float* __restrict__ g, const float* __restrict__ be,
    void* __restrict__ outp) {
  __shared__ float red[2][4];
  __shared__ float mu_s, sig_s;
  const int row = blockIdx.x;
  const int tid = threadIdx.x;
  const size_t off = (size_t)row * DM + tid * 4;

  const ushort4 ua = *(const ushort4*)(Ap + off);
  const ushort4 ub = *(const ushort4*)(Bp + off);
  float4 s = make_float4(bf2f(ua.x) + bf2f(ub.x), bf2f(ua.y) + bf2f(ub.y),
                         bf2f(ua.z) + bf2f(ub.z), bf2f(ua.w) + bf2f(ub.w));
  if (HASC) {
    const ushort4 uc = *(const ushort4*)(Cp + off);
    s.x += bf2f(uc.x); s.y += bf2f(uc.y); s.z += bf2f(uc.z); s.w += bf2f(uc.w);
  }
  if (HASB) {
    const float4 bb = *(const float4*)(bias + tid * 4);
    s.x += bb.x; s.y += bb.y; s.z += bb.z; s.w += bb.w;
  }

  float sum = s.x + s.y + s.z + s.w;
  float sq = s.x * s.x + s.y * s.y + s.z * s.z + s.w * s.w;
#pragma unroll
  for (int off2 = 32; off2 >= 1; off2 >>= 1) {
    sum += __shfl_xor(sum, off2);
    sq += __shfl_xor(sq, off2);
  }
  const int wid = tid >> 6;
  if ((tid & 63) == 0) { red[0][wid] = sum; red[1][wid] = sq; }
  __syncthreads();
  if (tid == 0) {
    float ts = red[0][0] + red[0][1] + red[0][2] + red[0][3];
    float tq = red[1][0] + red[1][1] + red[1][2] + red[1][3];
    float mu = ts * (1.f / DM);
    float var = tq * (1.f / DM) - mu * mu;
    mu_s = mu;
    sig_s = sqrtf(fmaxf(var, 0.f)) + 1e-6f;
  }
  __syncthreads();
  const float mu = mu_s, inv = 1.f / sig_s;
  const float4 gv = *(const float4*)(g + tid * 4);
  const float4 bv = *(const float4*)(be + tid * 4);
  float4 o;
  o.x = (s.x - mu) * inv * gv.x + bv.x;
  o.y = (s.y - mu) * inv * gv.y + bv.y;
  o.z = (s.z - mu) * inv * gv.z + bv.z;
  o.w = (s.w - mu) * inv * gv.w + bv.w;
  if (OBF) {
    u16* op = (u16*)outp + off;
    ushort4 o4;
    o4.x = f2bf(o.x); o4.y = f2bf(o.y); o4.z = f2bf(o.z); o4.w = f2bf(o.w);
    *(ushort4*)op = o4;
  } else {
    *(float4*)((float*)outp + off) = o;
  }
}

// ---------------------------------------------------------------------------
extern "C" void kernel_launch(void* const* d_in, const int* in_sizes, int n_in,
                              void* d_out, int out_size, void* d_ws,
                              size_t ws_size, hipStream_t stream) {
  const float* x  = (const float*)d_in[0];
  const int* mask = (const int*)d_in[1];
  const float* Wq = (const float*)d_in[2];
  const float* Wk = (const float*)d_in[3];
  const float* Wv = (const float*)d_in[4];
  const float* Wo = (const float*)d_in[5];
  const float* w1 = (const float*)d_in[6];
  const float* b1 = (const float*)d_in[7];
  const float* w2 = (const float*)d_in[8];
  const float* b2 = (const float*)d_in[9];
  const float* g1 = (const float*)d_in[10];
  const float* be1 = (const float*)d_in[11];
  const float* g2 = (const float*)d_in[12];
  const float* be2 = (const float*)d_in[13];
  float* out = (float*)d_out;
  float* ws = (float*)d_ws;

  // workspace layout (float offsets) — live-range-checked (round-14 proven):
  u16*   QKVb  = (u16*)(ws + 0);
  u16*   xb    = (u16*)(ws + 6291456);
  u16*   Wqkvb = (u16*)(ws + 8388608);
  u16*   Wob   = (u16*)(ws + 9961472);
  u16*   w1b   = (u16*)(ws + 10485760);
  u16*   w2b   = (u16*)(ws + 12582912);
  u16*   Obf   = (u16*)(ws + 14680064);
  u16*   X1a   = (u16*)(ws + 16777216);
  u16*   X1c   = (u16*)(ws + 18874368);
  u16*   X2b   = (u16*)(ws + 20971520);
  u16*   X3a   = (u16*)(ws + 23068672);
  u16*   X3c   = (u16*)(ws + 25165824);
  u16*   Hb    = (u16*)(ws + 0);

  const dim3 blk(256);

  cvt_all<<<8192, blk, 0, stream>>>(x, Wq, Wk, Wv, Wo, w1, w2,
                                    xb, Wqkvb, Wob, w1b, w2b);

  // fused QKV projection: [4096,3072] = xb @ Wqkvb^T, bf16 out
  gemm_bf16<128, 128, false, false><<<dim3(3072 / 128, MROWS / 128), blk, 0, stream>>>(
      xb, Wqkvb, nullptr, QKVb, MROWS, 3072, DM, DM);

  // MFMA flash attention v9 -> Obf
  attn_mfma<<<dim3(SEQ / 128, BSZ * NH), dim3(512), 0, stream>>>(QKVb, mask, Obf);

  // X1 = O @ Wo^T, split-K x2 (partials X1a, X1c; summed in LN1)
  gemm_bf16<64, 128, false, false><<<dim3(DM / 128, MROWS / 64, 2), blk, 0, stream>>>(
      Obf, Wob, nullptr, X1a, MROWS, DM, DM / 2, DM);

  // X2 = LN(X1a + X1c + xb) -> bf16
  ln_add<true, true, false><<<dim3(MROWS), blk, 0, stream>>>(
      X1a, xb, X1c, nullptr, g1, be1, X2b);

  // H = relu(X2 @ w1^T + b1) -> bf16
  gemm_bf16<128, 128, true, true><<<dim3(DFF / 128, MROWS / 128), blk, 0, stream>>>(
      X2b, w1b, b1, Hb, MROWS, DFF, DM, DM);

  // X3 = H @ w2^T, split-K x2 (partials X3a, X3c; bias b2 added in LN2)
  gemm_bf16<64, 128, false, false><<<dim3(DM / 128, MROWS / 64, 2), blk, 0, stream>>>(
      Hb, w2b, nullptr, X3a, MROWS, DM, DFF / 2, DFF);

  // out = LN(X2 + X3a + X3c + b2) -> fp32
  ln_add<false, true, true><<<dim3(MROWS), blk, 0, stream>>>(
      X2b, X3a, X3c, b2, g2, be2, out);
}